// Round 7
// baseline (736.498 us; speedup 1.0000x reference)
//
#include <hip/hip_runtime.h>

// TGCN forward, algebraically reduced (H0 = 0 => R/Wr dead, Z*H = 0):
//   deg[d] = #in-edges of d ; dinv = rsqrt(deg+1)
//   agg[d] = dinv[d] * ( sum_{e: dst=d} x[src]*dinv[src] + x[d]*dinv[d] )
//   Mz = Wz @ Lzw[0:256], cz = bz @ Lzw[0:256] + Lzb   (same for h)
//   Z = sigmoid(agg@Mz + cz), Ht = tanh(agg@Mh + ch)
//   h = relu((1-Z)*Ht) ; out = softmax(h @ Wo + bo)
//
// R1 -> R2: atomic scatter (2700us) -> CSR build + register gather.
// R2 -> R3: node_kernel 8-node tiling (313 -> ~129us).
// R3 -> R4: scatter 16x write amp -> 2-level bucket sort (793 -> 455us).
// R4 -> R5/R6: gate-split + s_load agg row; REGRESSED both times because the
// allocator kept VGPR_Count=48 (LDS-driven occupancy target) and re-streamed
// the 64-float M column from L1/L2 EVERY node (~12.8 TB of cache traffic).
// R6 -> R7: amdgpu_waves_per_eu(2,2) pins occupancy min=max=2 waves/EU so the
// allocator has no incentive to stay at 48 VGPRs -> m[64] register-resident.
// Confirmation signal: VGPR_Count >= 80. If still 48, next step is bf16 MFMA.

#define SHIFT 8
#define NPB   256          // nodes per bucket (=1<<SHIFT)
#define BMAX  512          // max buckets (n <= 131072 for 17-bit src packing)
#define TILE  8192         // edges per binning block
#define EPT   32           // edges per thread in binning

__global__ __launch_bounds__(256) void bucket_hist_kernel(const int* __restrict__ dsts,
                                                          int* __restrict__ bdeg,
                                                          int E, int B) {
    __shared__ int h[BMAX];
    for (int i = threadIdx.x; i < B; i += 256) h[i] = 0;
    __syncthreads();
    for (int e = blockIdx.x * 256 + threadIdx.x; e < E; e += gridDim.x * 256)
        atomicAdd(&h[((unsigned)dsts[e]) >> SHIFT], 1);
    __syncthreads();
    for (int i = threadIdx.x; i < B; i += 256)
        if (h[i]) atomicAdd(&bdeg[i], h[i]);
}

__global__ __launch_bounds__(512) void bucket_prefix_kernel(const int* __restrict__ bdeg,
                                                            int* __restrict__ bbase,
                                                            int* __restrict__ bcur, int B) {
    __shared__ int sv[BMAX];
    int tid = threadIdx.x;
    int v = (tid < B) ? bdeg[tid] : 0;
    sv[tid] = v;
    __syncthreads();
    for (int off = 1; off < BMAX; off <<= 1) {
        int t = (tid >= off) ? sv[tid - off] : 0;
        __syncthreads();
        sv[tid] += t;
        __syncthreads();
    }
    int excl = sv[tid] - v;
    if (tid < B) { bbase[tid] = excl; bcur[tid] = excl; }
}

// tile of 8192 edges: LDS histogram -> one global cursor atomic per
// (block,bucket) -> packed (dstLocal<<17 | src) written in contiguous runs
__global__ __launch_bounds__(256) void binning_kernel(const int* __restrict__ srcs,
                                                      const int* __restrict__ dsts,
                                                      int* __restrict__ bcur,
                                                      int* __restrict__ staging,
                                                      int E, int B) {
    __shared__ int h[BMAX];
    __shared__ int cur[BMAX];
    int tile0 = blockIdx.x * TILE;
    for (int i = threadIdx.x; i < B; i += 256) h[i] = 0;
    __syncthreads();
#pragma unroll 4
    for (int j = 0; j < EPT; ++j) {
        int e = tile0 + j * 256 + threadIdx.x;
        if (e < E) atomicAdd(&h[((unsigned)dsts[e]) >> SHIFT], 1);
    }
    __syncthreads();
    for (int i = threadIdx.x; i < B; i += 256)
        cur[i] = h[i] ? atomicAdd(&bcur[i], h[i]) : 0;
    __syncthreads();
#pragma unroll 4
    for (int j = 0; j < EPT; ++j) {
        int e = tile0 + j * 256 + threadIdx.x;
        if (e < E) {
            int d = dsts[e], s = srcs[e];
            int b = ((unsigned)d) >> SHIFT;
            int pos = atomicAdd(&cur[b], 1);
            staging[pos] = ((d & (NPB - 1)) << 17) | s;
        }
    }
}

// one block per bucket: per-node LDS histogram + scan -> start/deg/dinv,
// then scatter srcs inside the bucket's private csr window
__global__ __launch_bounds__(256) void finalize_kernel(const int* __restrict__ staging,
                                                       const int* __restrict__ bdeg,
                                                       const int* __restrict__ bbase,
                                                       int* __restrict__ csr,
                                                       int* __restrict__ deg,
                                                       int* __restrict__ start,
                                                       float* __restrict__ dinv, int n) {
    int b = blockIdx.x;
    int base = bbase[b], count = bdeg[b];
    __shared__ int nd[NPB];
    __shared__ int sv[NPB];
    __shared__ int ncur[NPB];
    int tid = threadIdx.x;
    nd[tid] = 0;
    __syncthreads();
    for (int i = tid; i < count; i += 256)
        atomicAdd(&nd[staging[base + i] >> 17], 1);
    __syncthreads();
    int d0 = nd[tid];
    sv[tid] = d0;
    __syncthreads();
    for (int off = 1; off < NPB; off <<= 1) {
        int t = (tid >= off) ? sv[tid - off] : 0;
        __syncthreads();
        sv[tid] += t;
        __syncthreads();
    }
    int excl = sv[tid] - d0;
    ncur[tid] = excl;
    int node = (b << SHIFT) + tid;
    if (node < n) {
        start[node] = base + excl;
        deg[node] = d0;
        dinv[node] = rsqrtf((float)d0 + 1.0f);
    }
    __syncthreads();
    for (int i = tid; i < count; i += 256) {
        int p = staging[base + i];
        int pos = atomicAdd(&ncur[p >> 17], 1);
        csr[base + pos] = p & 0x1FFFF;
    }
}

// one wave per node (4 waves/block). Lane = (edge_group 0..3) x (chan_quad 0..15).
__global__ __launch_bounds__(256) void gather_kernel(const int* __restrict__ csr,
                                                     const int* __restrict__ start,
                                                     const int* __restrict__ deg,
                                                     const float* __restrict__ x,
                                                     const float* __restrict__ dinv,
                                                     float* __restrict__ agg, int n) {
    int wave = threadIdx.x >> 6;
    int lane = threadIdx.x & 63;
    int node = blockIdx.x * 4 + wave;
    if (node >= n) return;
    int eg = lane >> 4;      // edge group 0..3
    int c  = lane & 15;      // float4 channel quad
    int s0 = start[node];
    int d  = deg[node];
    const float4* x4 = (const float4*)x;
    float4 acc = make_float4(0.f, 0.f, 0.f, 0.f);
    for (int base = 0; base < d; base += 4) {
        int e = base + eg;
        if (e < d) {
            int s = csr[s0 + e];
            float ds = dinv[s];
            float4 v = x4[(size_t)s * 16 + c];
            acc.x = fmaf(v.x, ds, acc.x);
            acc.y = fmaf(v.y, ds, acc.y);
            acc.z = fmaf(v.z, ds, acc.z);
            acc.w = fmaf(v.w, ds, acc.w);
        }
    }
    acc.x += __shfl_down(acc.x, 32); acc.y += __shfl_down(acc.y, 32);
    acc.z += __shfl_down(acc.z, 32); acc.w += __shfl_down(acc.w, 32);
    acc.x += __shfl_down(acc.x, 16); acc.y += __shfl_down(acc.y, 16);
    acc.z += __shfl_down(acc.z, 16); acc.w += __shfl_down(acc.w, 16);
    if (eg == 0) {
        float dn = dinv[node];
        float4 xv = x4[(size_t)node * 16 + c];
        float4 o;
        o.x = dn * fmaf(xv.x, dn, acc.x);
        o.y = dn * fmaf(xv.y, dn, acc.y);
        o.z = dn * fmaf(xv.z, dn, acc.z);
        o.w = dn * fmaf(xv.w, dn, acc.w);
        ((float4*)agg)[(size_t)node * 16 + c] = o;
    }
}

// Mz[k][j] = sum_t W[k][t] * L[t][j]   (k<64);  row k==64 computes the bias fold
__global__ __launch_bounds__(256) void build_m_kernel(
    const float* __restrict__ Wz, const float* __restrict__ bz,
    const float* __restrict__ Wh, const float* __restrict__ bh,
    const float* __restrict__ Lzw, const float* __restrict__ Lzb,
    const float* __restrict__ Lhw, const float* __restrict__ Lhb,
    float* __restrict__ Mz, float* __restrict__ cz,
    float* __restrict__ Mh, float* __restrict__ ch) {
    int j = threadIdx.x;
    int k = blockIdx.x;          // 0..64 (64 == bias row)
    int which = blockIdx.y;      // 0=z, 1=h
    const float* W  = which ? Wh  : Wz;
    const float* bv = which ? bh  : bz;
    const float* L  = which ? Lhw : Lzw;   // [512,256]; only rows 0..255 matter (H0=0)
    const float* Lb = which ? Lhb : Lzb;
    float* M  = which ? Mh : Mz;
    float* cv = which ? ch : cz;
    float acc = 0.f;
    if (k < 64) {
        for (int t = 0; t < 256; ++t) acc = fmaf(W[k * 256 + t], L[t * 256 + j], acc);
        M[k * 256 + j] = acc;
    } else {
        for (int t = 0; t < 256; ++t) acc = fmaf(bv[t], L[t * 256 + j], acc);
        cv[j] = acc + Lb[j];
    }
}

#define NB 16   // nodes per block-iteration (node_kernel)

// 512 threads: thread = (gate g = tid>>8, channel j = tid&255). 64-float M
// column register-resident. amdgpu_waves_per_eu(2,2) pins the allocator's
// occupancy target (min=max=2 waves/EU) so it has no reason to stay at 48
// VGPRs and re-stream M from cache per node (R5/R6 regression). agg row via
// wave-uniform s_load -> SGPR-operand v_fmac; 4 partial accumulators.
__attribute__((amdgpu_waves_per_eu(2, 2)))
__global__ __launch_bounds__(512) void node_kernel(
    const float* __restrict__ agg,
    const float* __restrict__ Mz, const float* __restrict__ cz,
    const float* __restrict__ Mh, const float* __restrict__ ch,
    const float* __restrict__ Wo, const float* __restrict__ bo,
    float* __restrict__ out, int n) {
    int tid = threadIdx.x;
    int gate = tid >> 8;        // 0 = z, 1 = h (wave-uniform)
    int j = tid & 255;
    const float* M = gate ? Mh : Mz;
    float m[64];
#pragma unroll
    for (int k = 0; k < 64; ++k) m[k] = M[k * 256 + j];
    float cj = (gate ? ch : cz)[j];
    __shared__ float sZ[NB][256];    // 16 KB
    __shared__ float sHt[NB][256];   // 16 KB
    __shared__ float sWo[4][256];    // 4 KB (planar: 2-way alias max = free)
    if (tid < 256) {
#pragma unroll
        for (int o = 0; o < 4; ++o) sWo[o][tid] = Wo[tid * 4 + o];
    }
    float bo0 = bo[0], bo1 = bo[1], bo2 = bo[2], bo3 = bo[3];
    int ntiles = (n + NB - 1) / NB;
    for (int tile = blockIdx.x; tile < ntiles; tile += gridDim.x) {
        int node0 = tile * NB;
        for (int nb = 0; nb < NB; ++nb) {
            int node = node0 + nb;                       // wave-uniform
            const float* arow = agg + (size_t)node * 64; // -> s_load
            float a0 = 0.f, a1 = 0.f, a2 = 0.f, a3 = 0.f;
#pragma unroll
            for (int k = 0; k < 64; k += 4) {
                a0 = fmaf(arow[k + 0], m[k + 0], a0);
                a1 = fmaf(arow[k + 1], m[k + 1], a1);
                a2 = fmaf(arow[k + 2], m[k + 2], a2);
                a3 = fmaf(arow[k + 3], m[k + 3], a3);
            }
            float acc = cj + ((a0 + a1) + (a2 + a3));
            if (gate == 0) {
                sZ[nb][j] = 1.0f / (1.0f + __expf(-acc));          // sigmoid
            } else {
                sHt[nb][j] = 1.0f - 2.0f / (1.0f + __expf(2.0f * acc)); // tanh
            }
        }
        __syncthreads();
        {   // head: 32 threads per node, 8 channels each
            int nb = tid >> 5, g = tid & 31;
            float l0 = 0.f, l1 = 0.f, l2 = 0.f, l3 = 0.f;
#pragma unroll
            for (int i = 0; i < 8; ++i) {
                int c = g + 32 * i;
                float z = sZ[nb][c];
                float ht = sHt[nb][c];
                float hv = fmaxf((1.0f - z) * ht, 0.0f);
                l0 = fmaf(hv, sWo[0][c], l0);
                l1 = fmaf(hv, sWo[1][c], l1);
                l2 = fmaf(hv, sWo[2][c], l2);
                l3 = fmaf(hv, sWo[3][c], l3);
            }
#pragma unroll
            for (int off = 16; off > 0; off >>= 1) {
                l0 += __shfl_down(l0, off, 32);
                l1 += __shfl_down(l1, off, 32);
                l2 += __shfl_down(l2, off, 32);
                l3 += __shfl_down(l3, off, 32);
            }
            int node = node0 + nb;
            if (g == 0 && node < n) {
                float v0 = l0 + bo0, v1 = l1 + bo1, v2 = l2 + bo2, v3 = l3 + bo3;
                float mx = fmaxf(fmaxf(v0, v1), fmaxf(v2, v3));
                float e0 = __expf(v0 - mx), e1 = __expf(v1 - mx);
                float e2 = __expf(v2 - mx), e3 = __expf(v3 - mx);
                float inv = 1.0f / (e0 + e1 + e2 + e3);
                float4 o;
                o.x = e0 * inv; o.y = e1 * inv; o.z = e2 * inv; o.w = e3 * inv;
                ((float4*)out)[node] = o;
            }
        }
        __syncthreads();
    }
}

extern "C" void kernel_launch(void* const* d_in, const int* in_sizes, int n_in,
                              void* d_out, int out_size, void* d_ws, size_t ws_size,
                              hipStream_t stream) {
    const float* x   = (const float*)d_in[0];
    const int*  eidx = (const int*)d_in[1];
    const float* Wz  = (const float*)d_in[2];
    const float* bz  = (const float*)d_in[3];
    // d_in[4]=Wr, d_in[5]=br : dead (H0 = 0)
    const float* Wh  = (const float*)d_in[6];
    const float* bh  = (const float*)d_in[7];
    const float* Lzw = (const float*)d_in[8];
    const float* Lzb = (const float*)d_in[9];
    // d_in[10]=Lrw, d_in[11]=Lrb : dead
    const float* Lhw = (const float*)d_in[12];
    const float* Lhb = (const float*)d_in[13];
    const float* Wo  = (const float*)d_in[14];
    const float* bo  = (const float*)d_in[15];
    float* out = (float*)d_out;

    int n = in_sizes[0] / 64;
    int E = in_sizes[1] / 2;
    const int* srcs = eidx;
    const int* dsts = eidx + E;
    int B = (n + NPB - 1) >> SHIFT;

    size_t na = ((size_t)n + 3) & ~(size_t)3;
    char* ws = (char*)d_ws;
    int*   deg   = (int*)ws;    ws += na * 4;
    int*   start = (int*)ws;    ws += na * 4;
    float* dinv  = (float*)ws;  ws += na * 4;
    int*   bdeg  = (int*)ws;    ws += BMAX * 4;
    int*   bbase = (int*)ws;    ws += BMAX * 4;
    int*   bcur  = (int*)ws;    ws += BMAX * 4;
    int*   csr   = (int*)ws;    ws += (size_t)E * 4;
    float* agg   = (float*)ws;  ws += (size_t)n * 64 * 4;
    int*   staging = (int*)agg;   // aliases agg: staging dead before gather writes
    float* Mz    = (float*)ws;  ws += 64 * 256 * 4;
    float* Mh    = (float*)ws;  ws += 64 * 256 * 4;
    float* cz    = (float*)ws;  ws += 256 * 4;
    float* ch    = (float*)ws;  ws += 256 * 4;

    hipMemsetAsync(bdeg, 0, BMAX * sizeof(int), stream);

    bucket_hist_kernel<<<1024, 256, 0, stream>>>(dsts, bdeg, E, B);
    bucket_prefix_kernel<<<1, BMAX, 0, stream>>>(bdeg, bbase, bcur, B);
    binning_kernel<<<(E + TILE - 1) / TILE, 256, 0, stream>>>(srcs, dsts, bcur,
                                                              staging, E, B);
    finalize_kernel<<<B, 256, 0, stream>>>(staging, bdeg, bbase, csr, deg, start,
                                           dinv, n);
    build_m_kernel<<<dim3(65, 2), 256, 0, stream>>>(Wz, bz, Wh, bh, Lzw, Lzb, Lhw,
                                                    Lhb, Mz, cz, Mh, ch);
    gather_kernel<<<(n + 3) / 4, 256, 0, stream>>>(csr, start, deg, x, dinv, agg, n);
    node_kernel<<<1024, 512, 0, stream>>>(agg, Mz, cz, Mh, ch, Wo, bo, out, n);
}

// Round 8
// 399.415 us; speedup vs baseline: 1.8439x; 1.8439x over previous
//
#include <hip/hip_runtime.h>

// TGCN forward, algebraically reduced (H0 = 0 => R/Wr dead, Z*H = 0):
//   deg[d] = #in-edges of d ; dinv = rsqrt(deg+1)
//   agg[d] = dinv[d] * ( sum_{e: dst=d} x[src]*dinv[src] + x[d]*dinv[d] )
//   M = [Wz@Lzw_top | Wh@Lhw_top]  (64x512, bf16, MFMA B-layout), cb = bias fold
//   out = softmax(relu((1-Z)*Ht) @ Wo + bo), Z/Ht from agg@M via MFMA
//
// R1 -> R2: atomic scatter (2700us) -> CSR build + register gather.
// R2 -> R3: node_kernel 8-node tiling (313 -> ~129us).
// R3 -> R4: scatter 16x write amp -> 2-level bucket sort (793 -> 455us).
// R4 -> R7: three rounds of fighting the register allocator over a 64-float
// per-thread M column: remat from L2 (48 VGPR) or occupancy starvation
// (waves_per_eu(2,2): s_load latency unhidden, VALUBusy 31%). Structurally
// dead. R8: node GEMM -> mfma_f32_16x16x32_bf16 (agg bf16 from gather,
// M bf16 in B-operand layout); per-thread footprint small at full occupancy.

#define SHIFT 8
#define NPB   256          // nodes per bucket (=1<<SHIFT)
#define BMAX  512          // max buckets (n <= 131072 for 17-bit src packing)
#define TILE  8192         // edges per binning block
#define EPT   32           // edges per thread in binning

typedef __attribute__((ext_vector_type(8))) short short8;
typedef __attribute__((ext_vector_type(4))) float floatx4;

__device__ __forceinline__ ushort f2b(float f) {   // fp32 -> bf16 RNE
    union { float f; unsigned u; } v; v.f = f;
    unsigned r = v.u + 0x7FFFu + ((v.u >> 16) & 1u);
    return (ushort)(r >> 16);
}

__global__ __launch_bounds__(256) void bucket_hist_kernel(const int* __restrict__ dsts,
                                                          int* __restrict__ bdeg,
                                                          int E, int B) {
    __shared__ int h[BMAX];
    for (int i = threadIdx.x; i < B; i += 256) h[i] = 0;
    __syncthreads();
    for (int e = blockIdx.x * 256 + threadIdx.x; e < E; e += gridDim.x * 256)
        atomicAdd(&h[((unsigned)dsts[e]) >> SHIFT], 1);
    __syncthreads();
    for (int i = threadIdx.x; i < B; i += 256)
        if (h[i]) atomicAdd(&bdeg[i], h[i]);
}

__global__ __launch_bounds__(512) void bucket_prefix_kernel(const int* __restrict__ bdeg,
                                                            int* __restrict__ bbase,
                                                            int* __restrict__ bcur, int B) {
    __shared__ int sv[BMAX];
    int tid = threadIdx.x;
    int v = (tid < B) ? bdeg[tid] : 0;
    sv[tid] = v;
    __syncthreads();
    for (int off = 1; off < BMAX; off <<= 1) {
        int t = (tid >= off) ? sv[tid - off] : 0;
        __syncthreads();
        sv[tid] += t;
        __syncthreads();
    }
    int excl = sv[tid] - v;
    if (tid < B) { bbase[tid] = excl; bcur[tid] = excl; }
}

// tile of 8192 edges: LDS histogram -> one global cursor atomic per
// (block,bucket) -> packed (dstLocal<<17 | src) written in contiguous runs
__global__ __launch_bounds__(256) void binning_kernel(const int* __restrict__ srcs,
                                                      const int* __restrict__ dsts,
                                                      int* __restrict__ bcur,
                                                      int* __restrict__ staging,
                                                      int E, int B) {
    __shared__ int h[BMAX];
    __shared__ int cur[BMAX];
    int tile0 = blockIdx.x * TILE;
    for (int i = threadIdx.x; i < B; i += 256) h[i] = 0;
    __syncthreads();
#pragma unroll 4
    for (int j = 0; j < EPT; ++j) {
        int e = tile0 + j * 256 + threadIdx.x;
        if (e < E) atomicAdd(&h[((unsigned)dsts[e]) >> SHIFT], 1);
    }
    __syncthreads();
    for (int i = threadIdx.x; i < B; i += 256)
        cur[i] = h[i] ? atomicAdd(&bcur[i], h[i]) : 0;
    __syncthreads();
#pragma unroll 4
    for (int j = 0; j < EPT; ++j) {
        int e = tile0 + j * 256 + threadIdx.x;
        if (e < E) {
            int d = dsts[e], s = srcs[e];
            int b = ((unsigned)d) >> SHIFT;
            int pos = atomicAdd(&cur[b], 1);
            staging[pos] = ((d & (NPB - 1)) << 17) | s;
        }
    }
}

// one block per bucket: per-node LDS histogram + scan -> start/deg/dinv,
// then scatter srcs inside the bucket's private csr window
__global__ __launch_bounds__(256) void finalize_kernel(const int* __restrict__ staging,
                                                       const int* __restrict__ bdeg,
                                                       const int* __restrict__ bbase,
                                                       int* __restrict__ csr,
                                                       int* __restrict__ deg,
                                                       int* __restrict__ start,
                                                       float* __restrict__ dinv, int n) {
    int b = blockIdx.x;
    int base = bbase[b], count = bdeg[b];
    __shared__ int nd[NPB];
    __shared__ int sv[NPB];
    __shared__ int ncur[NPB];
    int tid = threadIdx.x;
    nd[tid] = 0;
    __syncthreads();
    for (int i = tid; i < count; i += 256)
        atomicAdd(&nd[staging[base + i] >> 17], 1);
    __syncthreads();
    int d0 = nd[tid];
    sv[tid] = d0;
    __syncthreads();
    for (int off = 1; off < NPB; off <<= 1) {
        int t = (tid >= off) ? sv[tid - off] : 0;
        __syncthreads();
        sv[tid] += t;
        __syncthreads();
    }
    int excl = sv[tid] - d0;
    ncur[tid] = excl;
    int node = (b << SHIFT) + tid;
    if (node < n) {
        start[node] = base + excl;
        deg[node] = d0;
        dinv[node] = rsqrtf((float)d0 + 1.0f);
    }
    __syncthreads();
    for (int i = tid; i < count; i += 256) {
        int p = staging[base + i];
        int pos = atomicAdd(&ncur[p >> 17], 1);
        csr[base + pos] = p & 0x1FFFF;
    }
}

// one wave per node (4 waves/block). Lane = (edge_group 0..3) x (chan_quad 0..15).
// Output agg row in bf16 (MFMA A input; also halves write traffic).
__global__ __launch_bounds__(256) void gather_kernel(const int* __restrict__ csr,
                                                     const int* __restrict__ start,
                                                     const int* __restrict__ deg,
                                                     const float* __restrict__ x,
                                                     const float* __restrict__ dinv,
                                                     ushort* __restrict__ aggb, int n) {
    int wave = threadIdx.x >> 6;
    int lane = threadIdx.x & 63;
    int node = blockIdx.x * 4 + wave;
    if (node >= n) return;
    int eg = lane >> 4;      // edge group 0..3
    int c  = lane & 15;      // float4 channel quad
    int s0 = start[node];
    int d  = deg[node];
    const float4* x4 = (const float4*)x;
    float4 acc = make_float4(0.f, 0.f, 0.f, 0.f);
    for (int base = 0; base < d; base += 4) {
        int e = base + eg;
        if (e < d) {
            int s = csr[s0 + e];
            float ds = dinv[s];
            float4 v = x4[(size_t)s * 16 + c];
            acc.x = fmaf(v.x, ds, acc.x);
            acc.y = fmaf(v.y, ds, acc.y);
            acc.z = fmaf(v.z, ds, acc.z);
            acc.w = fmaf(v.w, ds, acc.w);
        }
    }
    acc.x += __shfl_down(acc.x, 32); acc.y += __shfl_down(acc.y, 32);
    acc.z += __shfl_down(acc.z, 32); acc.w += __shfl_down(acc.w, 32);
    acc.x += __shfl_down(acc.x, 16); acc.y += __shfl_down(acc.y, 16);
    acc.z += __shfl_down(acc.z, 16); acc.w += __shfl_down(acc.w, 16);
    if (eg == 0) {
        float dn = dinv[node];
        float4 xv = x4[(size_t)node * 16 + c];
        ushort4 o;
        o.x = f2b(dn * fmaf(xv.x, dn, acc.x));
        o.y = f2b(dn * fmaf(xv.y, dn, acc.y));
        o.z = f2b(dn * fmaf(xv.z, dn, acc.z));
        o.w = f2b(dn * fmaf(xv.w, dn, acc.w));
        ((ushort4*)(aggb + (size_t)node * 64))[c] = o;
    }
}

// Mb[j][k] = bf16( sum_t W[k][t] * L[t][j] ), j in [0,512): j<256 z, else h.
// Row-major [512][64] bf16 == MFMA B-operand order (lane n=j%16 reads
// k-chunk quad*8..+7 contiguously). cb[j] = bias fold.
__global__ __launch_bounds__(64) void build_m_kernel(
    const float* __restrict__ Wz, const float* __restrict__ bz,
    const float* __restrict__ Wh, const float* __restrict__ bh,
    const float* __restrict__ Lzw, const float* __restrict__ Lzb,
    const float* __restrict__ Lhw, const float* __restrict__ Lhb,
    ushort* __restrict__ Mb, float* __restrict__ cb) {
    int j = blockIdx.x;          // 0..511
    int k = threadIdx.x;         // 0..63
    int which = j >> 8;
    int jj = j & 255;
    const float* W  = which ? Wh  : Wz;
    const float* bv = which ? bh  : bz;
    const float* L  = which ? Lhw : Lzw;   // [512,256]; rows 0..255 only (H0=0)
    const float* Lb = which ? Lhb : Lzb;
    float acc = 0.f;
    for (int t = 0; t < 256; ++t) acc = fmaf(W[k * 256 + t], L[t * 256 + jj], acc);
    Mb[j * 64 + k] = f2b(acc);
    if (k == 0) {
        float a = 0.f;
        for (int t = 0; t < 256; ++t) a = fmaf(bv[t], L[t * 256 + jj], a);
        cb[j] = a + Lb[jj];
    }
}

// 512 threads = 8 waves. Wave w owns cols w*64..w*64+63 (4 cgs of 16):
// waves 0-3 compute z-gate (store 1-sigmoid), waves 4-7 tanh. Per 16-node
// tile: 2 A-frag loads + 8 MFMA per wave, epilogue to padded LDS, head =
// 32 threads/node. B-frags + bias register-resident for the whole kernel.
__global__ __launch_bounds__(512) void node_mfma_kernel(
    const ushort* __restrict__ aggb,   // [n][64] bf16
    const ushort* __restrict__ Mb,     // [512][64] bf16 (B layout)
    const float* __restrict__ cb,      // [512]
    const float* __restrict__ Wo, const float* __restrict__ bo,
    float* __restrict__ out, int n) {
    int tid  = threadIdx.x;
    int w    = tid >> 6;
    int lane = tid & 63;
    int nidx = lane & 15;
    int quad = lane >> 4;
    int gate = w >> 2;
    short8 bfrag[4][2];
    float cbv[4];
#pragma unroll
    for (int i = 0; i < 4; ++i) {
        int col = (w << 6) + (i << 4) + nidx;
#pragma unroll
        for (int s = 0; s < 2; ++s)
            bfrag[i][s] = *(const short8*)(Mb + col * 64 + s * 32 + quad * 8);
        cbv[i] = cb[col];
    }
    __shared__ float sZc[16][260];   // 1 - sigmoid  (pad 260: 2-way alias max)
    __shared__ float sHt[16][260];   // tanh
    __shared__ float sWo[4][256];
    if (tid < 256) {
#pragma unroll
        for (int o = 0; o < 4; ++o) sWo[o][tid] = Wo[tid * 4 + o];
    }
    float bo0 = bo[0], bo1 = bo[1], bo2 = bo[2], bo3 = bo[3];
    int ntiles = (n + 15) >> 4;
    for (int tile = blockIdx.x; tile < ntiles; tile += gridDim.x) {
        int node0 = tile << 4;
        int nodeA = node0 + nidx;
        if (nodeA >= n) nodeA = n - 1;   // clamp; stores are guarded
        const ushort* arow = aggb + (size_t)nodeA * 64;
        short8 a0 = *(const short8*)(arow + quad * 8);
        short8 a1 = *(const short8*)(arow + 32 + quad * 8);
#pragma unroll
        for (int i = 0; i < 4; ++i) {
            floatx4 c = {cbv[i], cbv[i], cbv[i], cbv[i]};
            c = __builtin_amdgcn_mfma_f32_16x16x32_bf16(a0, bfrag[i][0], c, 0, 0, 0);
            c = __builtin_amdgcn_mfma_f32_16x16x32_bf16(a1, bfrag[i][1], c, 0, 0, 0);
            int col = (w << 6) + (i << 4) + nidx;
#pragma unroll
            for (int r = 0; r < 4; ++r) {
                int row = (quad << 2) + r;                  // node within tile
                float v = c[r];
                if (gate == 0)
                    sZc[row][col] = 1.0f / (1.0f + __expf(v));          // 1-z
                else
                    sHt[row][col - 256] = 1.0f - 2.0f / (1.0f + __expf(2.0f * v));
            }
        }
        __syncthreads();
        {   // head: 32 threads per node, 8 channels each
            int nb = tid >> 5, g = tid & 31;
            float l0 = 0.f, l1 = 0.f, l2 = 0.f, l3 = 0.f;
#pragma unroll
            for (int ii = 0; ii < 8; ++ii) {
                int ch = g + 32 * ii;
                float hv = fmaxf(sZc[nb][ch] * sHt[nb][ch], 0.0f);
                l0 = fmaf(hv, sWo[0][ch], l0);
                l1 = fmaf(hv, sWo[1][ch], l1);
                l2 = fmaf(hv, sWo[2][ch], l2);
                l3 = fmaf(hv, sWo[3][ch], l3);
            }
#pragma unroll
            for (int off = 16; off > 0; off >>= 1) {
                l0 += __shfl_down(l0, off, 32);
                l1 += __shfl_down(l1, off, 32);
                l2 += __shfl_down(l2, off, 32);
                l3 += __shfl_down(l3, off, 32);
            }
            int node = node0 + nb;
            if (g == 0 && node < n) {
                float v0 = l0 + bo0, v1 = l1 + bo1, v2 = l2 + bo2, v3 = l3 + bo3;
                float mx = fmaxf(fmaxf(v0, v1), fmaxf(v2, v3));
                float e0 = __expf(v0 - mx), e1 = __expf(v1 - mx);
                float e2 = __expf(v2 - mx), e3 = __expf(v3 - mx);
                float inv = 1.0f / (e0 + e1 + e2 + e3);
                float4 o;
                o.x = e0 * inv; o.y = e1 * inv; o.z = e2 * inv; o.w = e3 * inv;
                ((float4*)out)[node] = o;
            }
        }
        __syncthreads();
    }
}

extern "C" void kernel_launch(void* const* d_in, const int* in_sizes, int n_in,
                              void* d_out, int out_size, void* d_ws, size_t ws_size,
                              hipStream_t stream) {
    const float* x   = (const float*)d_in[0];
    const int*  eidx = (const int*)d_in[1];
    const float* Wz  = (const float*)d_in[2];
    const float* bz  = (const float*)d_in[3];
    // d_in[4]=Wr, d_in[5]=br : dead (H0 = 0)
    const float* Wh  = (const float*)d_in[6];
    const float* bh  = (const float*)d_in[7];
    const float* Lzw = (const float*)d_in[8];
    const float* Lzb = (const float*)d_in[9];
    // d_in[10]=Lrw, d_in[11]=Lrb : dead
    const float* Lhw = (const float*)d_in[12];
    const float* Lhb = (const float*)d_in[13];
    const float* Wo  = (const float*)d_in[14];
    const float* bo  = (const float*)d_in[15];
    float* out = (float*)d_out;

    int n = in_sizes[0] / 64;
    int E = in_sizes[1] / 2;
    const int* srcs = eidx;
    const int* dsts = eidx + E;
    int B = (n + NPB - 1) >> SHIFT;

    size_t na = ((size_t)n + 3) & ~(size_t)3;
    size_t aggBytes = (size_t)n * 64 * 2;                 // bf16 agg
    size_t stageBytes = (size_t)E * 4;                    // staging (aliases agg)
    size_t bigBytes = (aggBytes > stageBytes ? aggBytes : stageBytes + 16) ;
    bigBytes = (bigBytes + 255) & ~(size_t)255;

    char* ws = (char*)d_ws;
    int*   deg   = (int*)ws;    ws += na * 4;
    int*   start = (int*)ws;    ws += na * 4;
    float* dinv  = (float*)ws;  ws += na * 4;
    int*   bdeg  = (int*)ws;    ws += BMAX * 4;
    int*   bbase = (int*)ws;    ws += BMAX * 4;
    int*   bcur  = (int*)ws;    ws += BMAX * 4;
    int*   csr   = (int*)ws;    ws += (size_t)E * 4;
    ushort* aggb = (ushort*)ws;
    int*   staging = (int*)aggb;   // aliases aggb: staging dead before gather
    ws += bigBytes;
    ushort* Mb   = (ushort*)ws; ws += 512 * 64 * 2;
    float* cb    = (float*)ws;  ws += 512 * 4;

    hipMemsetAsync(bdeg, 0, BMAX * sizeof(int), stream);

    bucket_hist_kernel<<<1024, 256, 0, stream>>>(dsts, bdeg, E, B);
    bucket_prefix_kernel<<<1, BMAX, 0, stream>>>(bdeg, bbase, bcur, B);
    binning_kernel<<<(E + TILE - 1) / TILE, 256, 0, stream>>>(srcs, dsts, bcur,
                                                              staging, E, B);
    finalize_kernel<<<B, 256, 0, stream>>>(staging, bdeg, bbase, csr, deg, start,
                                           dinv, n);
    build_m_kernel<<<512, 64, 0, stream>>>(Wz, bz, Wh, bh, Lzw, Lzb, Lhw, Lhb,
                                           Mb, cb);
    gather_kernel<<<(n + 3) / 4, 256, 0, stream>>>(csr, start, deg, x, dinv, aggb, n);
    node_mfma_kernel<<<2048, 512, 0, stream>>>(aggb, Mb, cb, Wo, bo, out, n);
}

// Round 9
// 352.253 us; speedup vs baseline: 2.0908x; 1.1339x over previous
//
#include <hip/hip_runtime.h>
#include <hip/hip_fp16.h>

// TGCN forward, algebraically reduced (H0 = 0 => R/Wr dead, Z*H = 0):
//   deg[d] = #in-edges of d ; dinv = rsqrt(deg+1)
//   xs[s]  = fp16( x[s] * dinv[s] )                      (R9 precompute)
//   agg[d] = bf16( dinv[d] * ( sum_{e: dst=d} xs[src] + xs[d]*dinv[d] ) )
//   M = [Wz@Lzw_top | Wh@Lhw_top]  (64x512, bf16, MFMA B-layout), cb = bias fold
//   out = softmax(relu((1-Z)*Ht) @ Wo + bo), Z/Ht from agg@M via MFMA
//
// R1 -> R2: atomic scatter (2700us) -> CSR build + register gather.
// R2 -> R3: node_kernel 8-node tiling (313 -> ~129us).
// R3 -> R4: scatter 16x write amp -> 2-level bucket sort (793 -> 455us).
// R4 -> R7: register-allocator fights over 64-float M column — dead end.
// R7 -> R8: node GEMM -> mfma_f32_16x16x32_bf16 (412 -> off top-5).
// R8 -> R9: gather is edge-payload-BW bound (FETCH 371MB, 819MB logical fp32
// rows). Pre-scale x by dinv into fp16 (error 5e-4/term, vs bf16 4e-3):
// row payload 256B -> 128B, per-edge dinv lookup + fmaf gone.

#define SHIFT 8
#define NPB   256          // nodes per bucket (=1<<SHIFT)
#define BMAX  512          // max buckets (n <= 131072 for 17-bit src packing)
#define TILE  8192         // edges per binning block
#define EPT   32           // edges per thread in binning

typedef __attribute__((ext_vector_type(8))) short short8;
typedef __attribute__((ext_vector_type(4))) float floatx4;

__device__ __forceinline__ ushort f2b(float f) {   // fp32 -> bf16 RNE
    union { float f; unsigned u; } v; v.f = f;
    unsigned r = v.u + 0x7FFFu + ((v.u >> 16) & 1u);
    return (ushort)(r >> 16);
}

__global__ __launch_bounds__(256) void bucket_hist_kernel(const int* __restrict__ dsts,
                                                          int* __restrict__ bdeg,
                                                          int E, int B) {
    __shared__ int h[BMAX];
    for (int i = threadIdx.x; i < B; i += 256) h[i] = 0;
    __syncthreads();
    for (int e = blockIdx.x * 256 + threadIdx.x; e < E; e += gridDim.x * 256)
        atomicAdd(&h[((unsigned)dsts[e]) >> SHIFT], 1);
    __syncthreads();
    for (int i = threadIdx.x; i < B; i += 256)
        if (h[i]) atomicAdd(&bdeg[i], h[i]);
}

__global__ __launch_bounds__(512) void bucket_prefix_kernel(const int* __restrict__ bdeg,
                                                            int* __restrict__ bbase,
                                                            int* __restrict__ bcur, int B) {
    __shared__ int sv[BMAX];
    int tid = threadIdx.x;
    int v = (tid < B) ? bdeg[tid] : 0;
    sv[tid] = v;
    __syncthreads();
    for (int off = 1; off < BMAX; off <<= 1) {
        int t = (tid >= off) ? sv[tid - off] : 0;
        __syncthreads();
        sv[tid] += t;
        __syncthreads();
    }
    int excl = sv[tid] - v;
    if (tid < B) { bbase[tid] = excl; bcur[tid] = excl; }
}

// tile of 8192 edges: LDS histogram -> one global cursor atomic per
// (block,bucket) -> packed (dstLocal<<17 | src) written in contiguous runs
__global__ __launch_bounds__(256) void binning_kernel(const int* __restrict__ srcs,
                                                      const int* __restrict__ dsts,
                                                      int* __restrict__ bcur,
                                                      int* __restrict__ staging,
                                                      int E, int B) {
    __shared__ int h[BMAX];
    __shared__ int cur[BMAX];
    int tile0 = blockIdx.x * TILE;
    for (int i = threadIdx.x; i < B; i += 256) h[i] = 0;
    __syncthreads();
#pragma unroll 4
    for (int j = 0; j < EPT; ++j) {
        int e = tile0 + j * 256 + threadIdx.x;
        if (e < E) atomicAdd(&h[((unsigned)dsts[e]) >> SHIFT], 1);
    }
    __syncthreads();
    for (int i = threadIdx.x; i < B; i += 256)
        cur[i] = h[i] ? atomicAdd(&bcur[i], h[i]) : 0;
    __syncthreads();
#pragma unroll 4
    for (int j = 0; j < EPT; ++j) {
        int e = tile0 + j * 256 + threadIdx.x;
        if (e < E) {
            int d = dsts[e], s = srcs[e];
            int b = ((unsigned)d) >> SHIFT;
            int pos = atomicAdd(&cur[b], 1);
            staging[pos] = ((d & (NPB - 1)) << 17) | s;
        }
    }
}

// one block per bucket: per-node LDS histogram + scan -> start/deg/dinv,
// then scatter srcs inside the bucket's private csr window
__global__ __launch_bounds__(256) void finalize_kernel(const int* __restrict__ staging,
                                                       const int* __restrict__ bdeg,
                                                       const int* __restrict__ bbase,
                                                       int* __restrict__ csr,
                                                       int* __restrict__ deg,
                                                       int* __restrict__ start,
                                                       float* __restrict__ dinv, int n) {
    int b = blockIdx.x;
    int base = bbase[b], count = bdeg[b];
    __shared__ int nd[NPB];
    __shared__ int sv[NPB];
    __shared__ int ncur[NPB];
    int tid = threadIdx.x;
    nd[tid] = 0;
    __syncthreads();
    for (int i = tid; i < count; i += 256)
        atomicAdd(&nd[staging[base + i] >> 17], 1);
    __syncthreads();
    int d0 = nd[tid];
    sv[tid] = d0;
    __syncthreads();
    for (int off = 1; off < NPB; off <<= 1) {
        int t = (tid >= off) ? sv[tid - off] : 0;
        __syncthreads();
        sv[tid] += t;
        __syncthreads();
    }
    int excl = sv[tid] - d0;
    ncur[tid] = excl;
    int node = (b << SHIFT) + tid;
    if (node < n) {
        start[node] = base + excl;
        deg[node] = d0;
        dinv[node] = rsqrtf((float)d0 + 1.0f);
    }
    __syncthreads();
    for (int i = tid; i < count; i += 256) {
        int p = staging[base + i];
        int pos = atomicAdd(&ncur[p >> 17], 1);
        csr[base + pos] = p & 0x1FFFF;
    }
}

// xs[s][c] = fp16( x[s][c] * dinv[s] ) — one thread per 4 channels
__global__ __launch_bounds__(256) void xs_kernel(const float* __restrict__ x,
                                                 const float* __restrict__ dinv,
                                                 __half* __restrict__ xs, int total) {
    int i = blockIdx.x * 256 + threadIdx.x;   // over n*16 float4 groups
    if (i >= total) return;
    float dn = dinv[i >> 4];
    float4 v = ((const float4*)x)[i];
    __half2 a = __floats2half2_rn(v.x * dn, v.y * dn);
    __half2 b = __floats2half2_rn(v.z * dn, v.w * dn);
    ((__half2*)xs)[i * 2 + 0] = a;
    ((__half2*)xs)[i * 2 + 1] = b;
}

// one wave per node (4 waves/block). Lane = (edge_group 0..7) x (chunk 0..7);
// each edge row is 128B fp16, one dwordx4 per lane covers 8 rows per wave
// instruction. Pure summation (x pre-scaled by dinv[src]); bf16 agg out.
__global__ __launch_bounds__(256) void gather_kernel(const int* __restrict__ csr,
                                                     const int* __restrict__ start,
                                                     const int* __restrict__ deg,
                                                     const __half* __restrict__ xs,
                                                     const float* __restrict__ dinv,
                                                     ushort* __restrict__ aggb, int n) {
    int wave = threadIdx.x >> 6;
    int lane = threadIdx.x & 63;
    int node = blockIdx.x * 4 + wave;
    if (node >= n) return;
    int eg = lane >> 3;      // edge group 0..7
    int c  = lane & 7;       // 16B chunk (8 halfs)
    int s0 = start[node];
    int d  = deg[node];
    float acc[8] = {0.f, 0.f, 0.f, 0.f, 0.f, 0.f, 0.f, 0.f};
    for (int base = 0; base < d; base += 8) {
        int e = base + eg;
        if (e < d) {
            int s = csr[s0 + e];
            union { uint4 u; __half2 h[4]; } p;
            p.u = *(const uint4*)(xs + (size_t)s * 64 + c * 8);
#pragma unroll
            for (int t = 0; t < 4; ++t) {
                float2 f = __half22float2(p.h[t]);
                acc[2 * t + 0] += f.x;
                acc[2 * t + 1] += f.y;
            }
        }
    }
    // reduce the 8 edge groups (lane stride 8) down to eg==0
#pragma unroll
    for (int off = 32; off >= 8; off >>= 1) {
#pragma unroll
        for (int t = 0; t < 8; ++t) acc[t] += __shfl_down(acc[t], off);
    }
    if (eg == 0) {
        float dn = dinv[node];
        union { uint4 u; __half2 h[4]; } p;
        p.u = *(const uint4*)(xs + (size_t)node * 64 + c * 8);
        uint4 o;
        unsigned* ow = (unsigned*)&o;
#pragma unroll
        for (int t = 0; t < 4; ++t) {
            float2 f = __half22float2(p.h[t]);
            float v0 = dn * fmaf(f.x, dn, acc[2 * t + 0]);
            float v1 = dn * fmaf(f.y, dn, acc[2 * t + 1]);
            ow[t] = (unsigned)f2b(v0) | ((unsigned)f2b(v1) << 16);
        }
        ((uint4*)(aggb + (size_t)node * 64))[c] = o;
    }
}

// Mb[j][k] = bf16( sum_t W[k][t] * L[t][j] ), j in [0,512): j<256 z, else h.
// Row-major [512][64] bf16 == MFMA B-operand order. cb[j] = bias fold.
__global__ __launch_bounds__(64) void build_m_kernel(
    const float* __restrict__ Wz, const float* __restrict__ bz,
    const float* __restrict__ Wh, const float* __restrict__ bh,
    const float* __restrict__ Lzw, const float* __restrict__ Lzb,
    const float* __restrict__ Lhw, const float* __restrict__ Lhb,
    ushort* __restrict__ Mb, float* __restrict__ cb) {
    int j = blockIdx.x;          // 0..511
    int k = threadIdx.x;         // 0..63
    int which = j >> 8;
    int jj = j & 255;
    const float* W  = which ? Wh  : Wz;
    const float* bv = which ? bh  : bz;
    const float* L  = which ? Lhw : Lzw;   // [512,256]; rows 0..255 only (H0=0)
    const float* Lb = which ? Lhb : Lzb;
    float acc = 0.f;
    for (int t = 0; t < 256; ++t) acc = fmaf(W[k * 256 + t], L[t * 256 + jj], acc);
    Mb[j * 64 + k] = f2b(acc);
    if (k == 0) {
        float a = 0.f;
        for (int t = 0; t < 256; ++t) a = fmaf(bv[t], L[t * 256 + jj], a);
        cb[j] = a + Lb[jj];
    }
}

// 512 threads = 8 waves. Wave w owns cols w*64..w*64+63 (4 cgs of 16):
// waves 0-3 compute z-gate (store 1-sigmoid), waves 4-7 tanh. Per 16-node
// tile: 2 A-frag loads + 8 MFMA per wave, epilogue to padded LDS, head =
// 32 threads/node. B-frags + bias register-resident for the whole kernel.
__global__ __launch_bounds__(512) void node_mfma_kernel(
    const ushort* __restrict__ aggb,   // [n][64] bf16
    const ushort* __restrict__ Mb,     // [512][64] bf16 (B layout)
    const float* __restrict__ cb,      // [512]
    const float* __restrict__ Wo, const float* __restrict__ bo,
    float* __restrict__ out, int n) {
    int tid  = threadIdx.x;
    int w    = tid >> 6;
    int lane = tid & 63;
    int nidx = lane & 15;
    int quad = lane >> 4;
    int gate = w >> 2;
    short8 bfrag[4][2];
    float cbv[4];
#pragma unroll
    for (int i = 0; i < 4; ++i) {
        int col = (w << 6) + (i << 4) + nidx;
#pragma unroll
        for (int s = 0; s < 2; ++s)
            bfrag[i][s] = *(const short8*)(Mb + col * 64 + s * 32 + quad * 8);
        cbv[i] = cb[col];
    }
    __shared__ float sZc[16][260];   // 1 - sigmoid  (pad 260: 2-way alias max)
    __shared__ float sHt[16][260];   // tanh
    __shared__ float sWo[4][256];
    if (tid < 256) {
#pragma unroll
        for (int o = 0; o < 4; ++o) sWo[o][tid] = Wo[tid * 4 + o];
    }
    float bo0 = bo[0], bo1 = bo[1], bo2 = bo[2], bo3 = bo[3];
    int ntiles = (n + 15) >> 4;
    for (int tile = blockIdx.x; tile < ntiles; tile += gridDim.x) {
        int node0 = tile << 4;
        int nodeA = node0 + nidx;
        if (nodeA >= n) nodeA = n - 1;   // clamp; stores are guarded
        const ushort* arow = aggb + (size_t)nodeA * 64;
        short8 a0 = *(const short8*)(arow + quad * 8);
        short8 a1 = *(const short8*)(arow + 32 + quad * 8);
#pragma unroll
        for (int i = 0; i < 4; ++i) {
            floatx4 c = {cbv[i], cbv[i], cbv[i], cbv[i]};
            c = __builtin_amdgcn_mfma_f32_16x16x32_bf16(a0, bfrag[i][0], c, 0, 0, 0);
            c = __builtin_amdgcn_mfma_f32_16x16x32_bf16(a1, bfrag[i][1], c, 0, 0, 0);
            int col = (w << 6) + (i << 4) + nidx;
#pragma unroll
            for (int r = 0; r < 4; ++r) {
                int row = (quad << 2) + r;                  // node within tile
                float v = c[r];
                if (gate == 0)
                    sZc[row][col] = 1.0f / (1.0f + __expf(v));          // 1-z
                else
                    sHt[row][col - 256] = 1.0f - 2.0f / (1.0f + __expf(2.0f * v));
            }
        }
        __syncthreads();
        {   // head: 32 threads per node, 8 channels each
            int nb = tid >> 5, g = tid & 31;
            float l0 = 0.f, l1 = 0.f, l2 = 0.f, l3 = 0.f;
#pragma unroll
            for (int ii = 0; ii < 8; ++ii) {
                int ch = g + 32 * ii;
                float hv = fmaxf(sZc[nb][ch] * sHt[nb][ch], 0.0f);
                l0 = fmaf(hv, sWo[0][ch], l0);
                l1 = fmaf(hv, sWo[1][ch], l1);
                l2 = fmaf(hv, sWo[2][ch], l2);
                l3 = fmaf(hv, sWo[3][ch], l3);
            }
#pragma unroll
            for (int off = 16; off > 0; off >>= 1) {
                l0 += __shfl_down(l0, off, 32);
                l1 += __shfl_down(l1, off, 32);
                l2 += __shfl_down(l2, off, 32);
                l3 += __shfl_down(l3, off, 32);
            }
            int node = node0 + nb;
            if (g == 0 && node < n) {
                float v0 = l0 + bo0, v1 = l1 + bo1, v2 = l2 + bo2, v3 = l3 + bo3;
                float mx = fmaxf(fmaxf(v0, v1), fmaxf(v2, v3));
                float e0 = __expf(v0 - mx), e1 = __expf(v1 - mx);
                float e2 = __expf(v2 - mx), e3 = __expf(v3 - mx);
                float inv = 1.0f / (e0 + e1 + e2 + e3);
                float4 o;
                o.x = e0 * inv; o.y = e1 * inv; o.z = e2 * inv; o.w = e3 * inv;
                ((float4*)out)[node] = o;
            }
        }
        __syncthreads();
    }
}

extern "C" void kernel_launch(void* const* d_in, const int* in_sizes, int n_in,
                              void* d_out, int out_size, void* d_ws, size_t ws_size,
                              hipStream_t stream) {
    const float* x   = (const float*)d_in[0];
    const int*  eidx = (const int*)d_in[1];
    const float* Wz  = (const float*)d_in[2];
    const float* bz  = (const float*)d_in[3];
    // d_in[4]=Wr, d_in[5]=br : dead (H0 = 0)
    const float* Wh  = (const float*)d_in[6];
    const float* bh  = (const float*)d_in[7];
    const float* Lzw = (const float*)d_in[8];
    const float* Lzb = (const float*)d_in[9];
    // d_in[10]=Lrw, d_in[11]=Lrb : dead
    const float* Lhw = (const float*)d_in[12];
    const float* Lhb = (const float*)d_in[13];
    const float* Wo  = (const float*)d_in[14];
    const float* bo  = (const float*)d_in[15];
    float* out = (float*)d_out;

    int n = in_sizes[0] / 64;
    int E = in_sizes[1] / 2;
    const int* srcs = eidx;
    const int* dsts = eidx + E;
    int B = (n + NPB - 1) >> SHIFT;

    size_t na = ((size_t)n + 3) & ~(size_t)3;
    size_t aggBytes = (size_t)n * 64 * 2;                 // bf16 agg
    size_t stageBytes = (size_t)E * 4 + 16;               // staging (aliases agg)
    size_t bigBytes = (aggBytes > stageBytes ? aggBytes : stageBytes);
    bigBytes = (bigBytes + 255) & ~(size_t)255;

    char* ws = (char*)d_ws;
    int*   deg   = (int*)ws;    ws += na * 4;
    int*   start = (int*)ws;    ws += na * 4;
    float* dinv  = (float*)ws;  ws += na * 4;
    int*   bdeg  = (int*)ws;    ws += BMAX * 4;
    int*   bbase = (int*)ws;    ws += BMAX * 4;
    int*   bcur  = (int*)ws;    ws += BMAX * 4;
    int*   csr   = (int*)ws;    ws += (size_t)E * 4;
    __half* xs   = (__half*)ws; ws += (size_t)n * 64 * 2;
    ushort* aggb = (ushort*)ws;
    int*   staging = (int*)aggb;   // aliases aggb: staging dead before gather
    ws += bigBytes;
    ushort* Mb   = (ushort*)ws; ws += 512 * 64 * 2;
    float* cb    = (float*)ws;  ws += 512 * 4;

    hipMemsetAsync(bdeg, 0, BMAX * sizeof(int), stream);

    bucket_hist_kernel<<<1024, 256, 0, stream>>>(dsts, bdeg, E, B);
    bucket_prefix_kernel<<<1, BMAX, 0, stream>>>(bdeg, bbase, bcur, B);
    binning_kernel<<<(E + TILE - 1) / TILE, 256, 0, stream>>>(srcs, dsts, bcur,
                                                              staging, E, B);
    finalize_kernel<<<B, 256, 0, stream>>>(staging, bdeg, bbase, csr, deg, start,
                                           dinv, n);
    build_m_kernel<<<512, 64, 0, stream>>>(Wz, bz, Wh, bh, Lzw, Lzb, Lhw, Lhb,
                                           Mb, cb);
    xs_kernel<<<(n * 16 + 255) / 256, 256, 0, stream>>>(x, dinv, xs, n * 16);
    gather_kernel<<<(n + 3) / 4, 256, 0, stream>>>(csr, start, deg, xs, dinv,
                                                   aggb, n);
    node_mfma_kernel<<<2048, 512, 0, stream>>>(aggb, Mb, cb, Wo, bo, out, n);
}

// Round 10
// 335.408 us; speedup vs baseline: 2.1958x; 1.0502x over previous
//
#include <hip/hip_runtime.h>
#include <hip/hip_fp16.h>

// TGCN forward, algebraically reduced (H0 = 0 => R/Wr dead, Z*H = 0):
//   deg[d] = #in-edges of d ; dinv = rsqrt(deg+1)
//   xs[s]  = fp16( x[s] * dinv[s] )
//   agg[d] = bf16( dinv[d] * ( sum_{e: dst=d} xs[src] + xs[d]*dinv[d] ) )
//   M = [Wz@Lzw_top | Wh@Lhw_top]  (64x512, bf16, MFMA B-layout), cb = bias fold
//   out = softmax(relu((1-Z)*Ht) @ Wo + bo), Z/Ht from agg@M via MFMA
//
// R1 -> R2: atomic scatter (2700us) -> CSR build + register gather.
// R3 -> R4: scatter 16x write amp -> 2-level bucket sort (793 -> 455us).
// R4 -> R7: register-allocator fights over 64-float M column — dead end.
// R7 -> R8: node GEMM -> mfma_f32_16x16x32_bf16 (412 -> off top-5).
// R8 -> R9: xs = fp16(x*dinv) precompute: row 256B -> 128B (gather 124 -> 75).
// R9 -> R10: gather was latency-bound (14.3 cyc/edge vs 4.5 VALU floor,
// VALUBusy 41%): per-iter dependent csr load removed (one coalesced 64-index
// load + shfl) + 2x unrolled predicated row loads. binning 391 blocks (6
// waves/CU) -> TILE 4096 (12 waves/CU) + LDS dst cache. finalize -> 512 thr.

#define SHIFT 8
#define NPB   256          // nodes per bucket (=1<<SHIFT)
#define BMAX  512          // max buckets (n <= 131072 for 17-bit src packing)
#define TILE  4096         // edges per binning block (R10: was 8192)
#define EPT   16           // edges per thread in binning

typedef __attribute__((ext_vector_type(8))) short short8;
typedef __attribute__((ext_vector_type(4))) float floatx4;

__device__ __forceinline__ ushort f2b(float f) {   // fp32 -> bf16 RNE
    union { float f; unsigned u; } v; v.f = f;
    unsigned r = v.u + 0x7FFFu + ((v.u >> 16) & 1u);
    return (ushort)(r >> 16);
}

__global__ __launch_bounds__(256) void bucket_hist_kernel(const int* __restrict__ dsts,
                                                          int* __restrict__ bdeg,
                                                          int E, int B) {
    __shared__ int h[BMAX];
    for (int i = threadIdx.x; i < B; i += 256) h[i] = 0;
    __syncthreads();
    for (int e = blockIdx.x * 256 + threadIdx.x; e < E; e += gridDim.x * 256)
        atomicAdd(&h[((unsigned)dsts[e]) >> SHIFT], 1);
    __syncthreads();
    for (int i = threadIdx.x; i < B; i += 256)
        if (h[i]) atomicAdd(&bdeg[i], h[i]);
}

__global__ __launch_bounds__(512) void bucket_prefix_kernel(const int* __restrict__ bdeg,
                                                            int* __restrict__ bbase,
                                                            int* __restrict__ bcur, int B) {
    __shared__ int sv[BMAX];
    int tid = threadIdx.x;
    int v = (tid < B) ? bdeg[tid] : 0;
    sv[tid] = v;
    __syncthreads();
    for (int off = 1; off < BMAX; off <<= 1) {
        int t = (tid >= off) ? sv[tid - off] : 0;
        __syncthreads();
        sv[tid] += t;
        __syncthreads();
    }
    int excl = sv[tid] - v;
    if (tid < B) { bbase[tid] = excl; bcur[tid] = excl; }
}

// tile of 4096 edges: LDS histogram (dsts cached to LDS) -> one global cursor
// atomic per (block,bucket) -> packed (dstLocal<<17 | src) contiguous runs
__global__ __launch_bounds__(256) void binning_kernel(const int* __restrict__ srcs,
                                                      const int* __restrict__ dsts,
                                                      int* __restrict__ bcur,
                                                      int* __restrict__ staging,
                                                      int E, int B) {
    __shared__ int h[BMAX];
    __shared__ int cur[BMAX];
    __shared__ int sdst[TILE];
    int tile0 = blockIdx.x * TILE;
    for (int i = threadIdx.x; i < B; i += 256) h[i] = 0;
    __syncthreads();
#pragma unroll 4
    for (int j = 0; j < EPT; ++j) {
        int li = j * 256 + threadIdx.x;
        int e = tile0 + li;
        if (e < E) {
            int d = dsts[e];
            sdst[li] = d;
            atomicAdd(&h[((unsigned)d) >> SHIFT], 1);
        }
    }
    __syncthreads();
    for (int i = threadIdx.x; i < B; i += 256)
        cur[i] = h[i] ? atomicAdd(&bcur[i], h[i]) : 0;
    __syncthreads();
#pragma unroll 4
    for (int j = 0; j < EPT; ++j) {
        int li = j * 256 + threadIdx.x;
        int e = tile0 + li;
        if (e < E) {
            int d = sdst[li], s = srcs[e];
            int b = ((unsigned)d) >> SHIFT;
            int pos = atomicAdd(&cur[b], 1);
            staging[pos] = ((d & (NPB - 1)) << 17) | s;
        }
    }
}

// one block (512 thr) per bucket: per-node LDS histogram + scan ->
// start/deg/dinv, then scatter srcs inside the bucket's private csr window
__global__ __launch_bounds__(512) void finalize_kernel(const int* __restrict__ staging,
                                                       const int* __restrict__ bdeg,
                                                       const int* __restrict__ bbase,
                                                       int* __restrict__ csr,
                                                       int* __restrict__ deg,
                                                       int* __restrict__ start,
                                                       float* __restrict__ dinv, int n) {
    int b = blockIdx.x;
    int base = bbase[b], count = bdeg[b];
    __shared__ int nd[NPB];
    __shared__ int sv[NPB];
    __shared__ int ncur[NPB];
    int tid = threadIdx.x;
    if (tid < NPB) nd[tid] = 0;
    __syncthreads();
    for (int i = tid; i < count; i += 512)
        atomicAdd(&nd[staging[base + i] >> 17], 1);
    __syncthreads();
    int d0 = 0;
    if (tid < NPB) { d0 = nd[tid]; sv[tid] = d0; }
    __syncthreads();
    for (int off = 1; off < NPB; off <<= 1) {
        int t = 0;
        if (tid < NPB && tid >= off) t = sv[tid - off];
        __syncthreads();
        if (tid < NPB) sv[tid] += t;
        __syncthreads();
    }
    if (tid < NPB) {
        int excl = sv[tid] - d0;
        ncur[tid] = excl;
        int node = (b << SHIFT) + tid;
        if (node < n) {
            start[node] = base + excl;
            deg[node] = d0;
            dinv[node] = rsqrtf((float)d0 + 1.0f);
        }
    }
    __syncthreads();
    for (int i = tid; i < count; i += 512) {
        int p = staging[base + i];
        int pos = atomicAdd(&ncur[p >> 17], 1);
        csr[base + pos] = p & 0x1FFFF;
    }
}

// xs[s][c] = fp16( x[s][c] * dinv[s] ) — one thread per 4 channels
__global__ __launch_bounds__(256) void xs_kernel(const float* __restrict__ x,
                                                 const float* __restrict__ dinv,
                                                 __half* __restrict__ xs, int total) {
    int i = blockIdx.x * 256 + threadIdx.x;   // over n*16 float4 groups
    if (i >= total) return;
    float dn = dinv[i >> 4];
    float4 v = ((const float4*)x)[i];
    __half2 a = __floats2half2_rn(v.x * dn, v.y * dn);
    __half2 b = __floats2half2_rn(v.z * dn, v.w * dn);
    ((__half2*)xs)[i * 2 + 0] = a;
    ((__half2*)xs)[i * 2 + 1] = b;
}

// one wave per node. Lane = (edge_group 0..7) x (chunk 0..7). Per 64-edge
// chunk: ONE coalesced csr load (indices distributed via shfl — no per-iter
// dependent csr load), row loop 2x unrolled with weight-predication so two
// independent 16B row loads are in flight. Summation order identical to R9.
__global__ __launch_bounds__(256) void gather_kernel(const int* __restrict__ csr,
                                                     const int* __restrict__ start,
                                                     const int* __restrict__ deg,
                                                     const __half* __restrict__ xs,
                                                     const float* __restrict__ dinv,
                                                     ushort* __restrict__ aggb, int n) {
    int wave = threadIdx.x >> 6;
    int lane = threadIdx.x & 63;
    int node = blockIdx.x * 4 + wave;
    if (node >= n) return;
    int eg = lane >> 3;      // edge group 0..7
    int c  = lane & 7;       // 16B chunk (8 halfs)
    int s0 = start[node];
    int d  = deg[node];
    float acc[8] = {0.f, 0.f, 0.f, 0.f, 0.f, 0.f, 0.f, 0.f};
    for (int chunk = 0; chunk < d; chunk += 64) {
        int nrem = d - chunk;
        if (nrem > 64) nrem = 64;
        int ml = lane < nrem ? lane : nrem - 1;
        int idx = csr[s0 + chunk + ml];          // one coalesced load / chunk
        for (int base = 0; base < nrem; base += 16) {
            int e0 = base + eg;
            int e1 = base + 8 + eg;
            int i0 = __shfl(idx, e0 < nrem ? e0 : nrem - 1);
            int i1 = __shfl(idx, e1 < nrem ? e1 : nrem - 1);
            float w0 = e0 < nrem ? 1.0f : 0.0f;
            float w1 = e1 < nrem ? 1.0f : 0.0f;
            union { uint4 u; __half2 h[4]; } p0, p1;
            p0.u = *(const uint4*)(xs + (size_t)i0 * 64 + c * 8);
            p1.u = *(const uint4*)(xs + (size_t)i1 * 64 + c * 8);
#pragma unroll
            for (int t = 0; t < 4; ++t) {
                float2 f = __half22float2(p0.h[t]);
                acc[2 * t + 0] = fmaf(f.x, w0, acc[2 * t + 0]);
                acc[2 * t + 1] = fmaf(f.y, w0, acc[2 * t + 1]);
            }
#pragma unroll
            for (int t = 0; t < 4; ++t) {
                float2 f = __half22float2(p1.h[t]);
                acc[2 * t + 0] = fmaf(f.x, w1, acc[2 * t + 0]);
                acc[2 * t + 1] = fmaf(f.y, w1, acc[2 * t + 1]);
            }
        }
    }
    // reduce the 8 edge groups (lane stride 8) down to eg==0
#pragma unroll
    for (int off = 32; off >= 8; off >>= 1) {
#pragma unroll
        for (int t = 0; t < 8; ++t) acc[t] += __shfl_down(acc[t], off);
    }
    if (eg == 0) {
        float dn = dinv[node];
        union { uint4 u; __half2 h[4]; } p;
        p.u = *(const uint4*)(xs + (size_t)node * 64 + c * 8);
        uint4 o;
        unsigned* ow = (unsigned*)&o;
#pragma unroll
        for (int t = 0; t < 4; ++t) {
            float2 f = __half22float2(p.h[t]);
            float v0 = dn * fmaf(f.x, dn, acc[2 * t + 0]);
            float v1 = dn * fmaf(f.y, dn, acc[2 * t + 1]);
            ow[t] = (unsigned)f2b(v0) | ((unsigned)f2b(v1) << 16);
        }
        ((uint4*)(aggb + (size_t)node * 64))[c] = o;
    }
}

// Mb[j][k] = bf16( sum_t W[k][t] * L[t][j] ), j in [0,512): j<256 z, else h.
// Row-major [512][64] bf16 == MFMA B-operand order. cb[j] = bias fold.
__global__ __launch_bounds__(64) void build_m_kernel(
    const float* __restrict__ Wz, const float* __restrict__ bz,
    const float* __restrict__ Wh, const float* __restrict__ bh,
    const float* __restrict__ Lzw, const float* __restrict__ Lzb,
    const float* __restrict__ Lhw, const float* __restrict__ Lhb,
    ushort* __restrict__ Mb, float* __restrict__ cb) {
    int j = blockIdx.x;          // 0..511
    int k = threadIdx.x;         // 0..63
    int which = j >> 8;
    int jj = j & 255;
    const float* W  = which ? Wh  : Wz;
    const float* bv = which ? bh  : bz;
    const float* L  = which ? Lhw : Lzw;   // [512,256]; rows 0..255 only (H0=0)
    const float* Lb = which ? Lhb : Lzb;
    float acc = 0.f;
    for (int t = 0; t < 256; ++t) acc = fmaf(W[k * 256 + t], L[t * 256 + jj], acc);
    Mb[j * 64 + k] = f2b(acc);
    if (k == 0) {
        float a = 0.f;
        for (int t = 0; t < 256; ++t) a = fmaf(bv[t], L[t * 256 + jj], a);
        cb[j] = a + Lb[jj];
    }
}

// 512 threads = 8 waves. Wave w owns cols w*64..w*64+63 (4 cgs of 16):
// waves 0-3 compute z-gate (store 1-sigmoid), waves 4-7 tanh. Per 16-node
// tile: 2 A-frag loads + 8 MFMA per wave, epilogue to padded LDS, head =
// 32 threads/node. B-frags + bias register-resident for the whole kernel.
__global__ __launch_bounds__(512) void node_mfma_kernel(
    const ushort* __restrict__ aggb,   // [n][64] bf16
    const ushort* __restrict__ Mb,     // [512][64] bf16 (B layout)
    const float* __restrict__ cb,      // [512]
    const float* __restrict__ Wo, const float* __restrict__ bo,
    float* __restrict__ out, int n) {
    int tid  = threadIdx.x;
    int w    = tid >> 6;
    int lane = tid & 63;
    int nidx = lane & 15;
    int quad = lane >> 4;
    int gate = w >> 2;
    short8 bfrag[4][2];
    float cbv[4];
#pragma unroll
    for (int i = 0; i < 4; ++i) {
        int col = (w << 6) + (i << 4) + nidx;
#pragma unroll
        for (int s = 0; s < 2; ++s)
            bfrag[i][s] = *(const short8*)(Mb + col * 64 + s * 32 + quad * 8);
        cbv[i] = cb[col];
    }
    __shared__ float sZc[16][260];   // 1 - sigmoid  (pad 260: 2-way alias max)
    __shared__ float sHt[16][260];   // tanh
    __shared__ float sWo[4][256];
    if (tid < 256) {
#pragma unroll
        for (int o = 0; o < 4; ++o) sWo[o][tid] = Wo[tid * 4 + o];
    }
    float bo0 = bo[0], bo1 = bo[1], bo2 = bo[2], bo3 = bo[3];
    int ntiles = (n + 15) >> 4;
    for (int tile = blockIdx.x; tile < ntiles; tile += gridDim.x) {
        int node0 = tile << 4;
        int nodeA = node0 + nidx;
        if (nodeA >= n) nodeA = n - 1;   // clamp; stores are guarded
        const ushort* arow = aggb + (size_t)nodeA * 64;
        short8 a0 = *(const short8*)(arow + quad * 8);
        short8 a1 = *(const short8*)(arow + 32 + quad * 8);
#pragma unroll
        for (int i = 0; i < 4; ++i) {
            floatx4 c = {cbv[i], cbv[i], cbv[i], cbv[i]};
            c = __builtin_amdgcn_mfma_f32_16x16x32_bf16(a0, bfrag[i][0], c, 0, 0, 0);
            c = __builtin_amdgcn_mfma_f32_16x16x32_bf16(a1, bfrag[i][1], c, 0, 0, 0);
            int col = (w << 6) + (i << 4) + nidx;
#pragma unroll
            for (int r = 0; r < 4; ++r) {
                int row = (quad << 2) + r;                  // node within tile
                float v = c[r];
                if (gate == 0)
                    sZc[row][col] = 1.0f / (1.0f + __expf(v));          // 1-z
                else
                    sHt[row][col - 256] = 1.0f - 2.0f / (1.0f + __expf(2.0f * v));
            }
        }
        __syncthreads();
        {   // head: 32 threads per node, 8 channels each
            int nb = tid >> 5, g = tid & 31;
            float l0 = 0.f, l1 = 0.f, l2 = 0.f, l3 = 0.f;
#pragma unroll
            for (int ii = 0; ii < 8; ++ii) {
                int ch = g + 32 * ii;
                float hv = fmaxf(sZc[nb][ch] * sHt[nb][ch], 0.0f);
                l0 = fmaf(hv, sWo[0][ch], l0);
                l1 = fmaf(hv, sWo[1][ch], l1);
                l2 = fmaf(hv, sWo[2][ch], l2);
                l3 = fmaf(hv, sWo[3][ch], l3);
            }
#pragma unroll
            for (int off = 16; off > 0; off >>= 1) {
                l0 += __shfl_down(l0, off, 32);
                l1 += __shfl_down(l1, off, 32);
                l2 += __shfl_down(l2, off, 32);
                l3 += __shfl_down(l3, off, 32);
            }
            int node = node0 + nb;
            if (g == 0 && node < n) {
                float v0 = l0 + bo0, v1 = l1 + bo1, v2 = l2 + bo2, v3 = l3 + bo3;
                float mx = fmaxf(fmaxf(v0, v1), fmaxf(v2, v3));
                float e0 = __expf(v0 - mx), e1 = __expf(v1 - mx);
                float e2 = __expf(v2 - mx), e3 = __expf(v3 - mx);
                float inv = 1.0f / (e0 + e1 + e2 + e3);
                float4 o;
                o.x = e0 * inv; o.y = e1 * inv; o.z = e2 * inv; o.w = e3 * inv;
                ((float4*)out)[node] = o;
            }
        }
        __syncthreads();
    }
}

extern "C" void kernel_launch(void* const* d_in, const int* in_sizes, int n_in,
                              void* d_out, int out_size, void* d_ws, size_t ws_size,
                              hipStream_t stream) {
    const float* x   = (const float*)d_in[0];
    const int*  eidx = (const int*)d_in[1];
    const float* Wz  = (const float*)d_in[2];
    const float* bz  = (const float*)d_in[3];
    // d_in[4]=Wr, d_in[5]=br : dead (H0 = 0)
    const float* Wh  = (const float*)d_in[6];
    const float* bh  = (const float*)d_in[7];
    const float* Lzw = (const float*)d_in[8];
    const float* Lzb = (const float*)d_in[9];
    // d_in[10]=Lrw, d_in[11]=Lrb : dead
    const float* Lhw = (const float*)d_in[12];
    const float* Lhb = (const float*)d_in[13];
    const float* Wo  = (const float*)d_in[14];
    const float* bo  = (const float*)d_in[15];
    float* out = (float*)d_out;

    int n = in_sizes[0] / 64;
    int E = in_sizes[1] / 2;
    const int* srcs = eidx;
    const int* dsts = eidx + E;
    int B = (n + NPB - 1) >> SHIFT;

    size_t na = ((size_t)n + 3) & ~(size_t)3;
    size_t aggBytes = (size_t)n * 64 * 2;                 // bf16 agg
    size_t stageBytes = (size_t)E * 4 + 16;               // staging (aliases agg)
    size_t bigBytes = (aggBytes > stageBytes ? aggBytes : stageBytes);
    bigBytes = (bigBytes + 255) & ~(size_t)255;

    char* ws = (char*)d_ws;
    int*   deg   = (int*)ws;    ws += na * 4;
    int*   start = (int*)ws;    ws += na * 4;
    float* dinv  = (float*)ws;  ws += na * 4;
    int*   bdeg  = (int*)ws;    ws += BMAX * 4;
    int*   bbase = (int*)ws;    ws += BMAX * 4;
    int*   bcur  = (int*)ws;    ws += BMAX * 4;
    int*   csr   = (int*)ws;    ws += (size_t)E * 4;
    __half* xs   = (__half*)ws; ws += (size_t)n * 64 * 2;
    ushort* aggb = (ushort*)ws;
    int*   staging = (int*)aggb;   // aliases aggb: staging dead before gather
    ws += bigBytes;
    ushort* Mb   = (ushort*)ws; ws += 512 * 64 * 2;
    float* cb    = (float*)ws;  ws += 512 * 4;

    hipMemsetAsync(bdeg, 0, BMAX * sizeof(int), stream);

    bucket_hist_kernel<<<1024, 256, 0, stream>>>(dsts, bdeg, E, B);
    bucket_prefix_kernel<<<1, BMAX, 0, stream>>>(bdeg, bbase, bcur, B);
    binning_kernel<<<(E + TILE - 1) / TILE, 256, 0, stream>>>(srcs, dsts, bcur,
                                                              staging, E, B);
    finalize_kernel<<<B, 512, 0, stream>>>(staging, bdeg, bbase, csr, deg, start,
                                           dinv, n);
    build_m_kernel<<<512, 64, 0, stream>>>(Wz, bz, Wh, bh, Lzw, Lzb, Lhw, Lhb,
                                           Mb, cb);
    xs_kernel<<<(n * 16 + 255) / 256, 256, 0, stream>>>(x, dinv, xs, n * 16);
    gather_kernel<<<(n + 3) / 4, 256, 0, stream>>>(csr, start, deg, xs, dinv,
                                                   aggb, n);
    node_mfma_kernel<<<2048, 512, 0, stream>>>(aggb, Mb, cb, Wo, bo, out, n);
}

// Round 11
// 320.417 us; speedup vs baseline: 2.2986x; 1.0468x over previous
//
#include <hip/hip_runtime.h>
#include <hip/hip_fp16.h>

// TGCN forward, algebraically reduced (H0 = 0 => R/Wr dead, Z*H = 0):
//   deg[d] = #in-edges of d ; dinv = rsqrt(deg+1)
//   xs[s]  = fp16( x[s] * dinv[s] )
//   agg[d] = bf16( dinv[d] * ( sum_{e: dst=d} xs[src] + xs[d]*dinv[d] ) )
//   M = [Wz@Lzw_top | Wh@Lhw_top]  (64x512, bf16, MFMA B-layout), cb = bias fold
//   out = softmax(relu((1-Z)*Ht) @ Wo + bo), Z/Ht from agg@M via MFMA
//
// R1 -> R2: atomic scatter (2700us) -> CSR build + register gather.
// R3 -> R4: scatter 16x write amp -> 2-level bucket sort (793 -> 455us).
// R4 -> R7: register-allocator fights over 64-float M column — dead end.
// R7 -> R8: node GEMM -> mfma_f32_16x16x32_bf16 (412 -> off top-5).
// R8 -> R9: xs = fp16(x*dinv): row 256B -> 128B (gather 124 -> 75).
// R9 -> R10: gather de-latency (75 -> <64); but TILE 4096 BACKFIRED: 42B
// staging runs -> 6x write amp, binning 67us write-bound.
// R10 -> R11: binning TILE back to 8192 (84B runs, ~2x amp), sdst cache
// dropped (4KB LDS). node_mfma re-split: wave owns 32 cols x BOTH gates so
// h=relu((1-z)*ht) forms in-register; only one 16.6KB h-plane hits LDS
// (was 32KB z+ht planes) -> 7 blocks/CU.

#define SHIFT 8
#define NPB   256          // nodes per bucket (=1<<SHIFT)
#define BMAX  512          // max buckets (n <= 131072 for 17-bit src packing)
#define TILE  8192         // edges per binning block
#define EPT   32           // edges per thread in binning

typedef __attribute__((ext_vector_type(8))) short short8;
typedef __attribute__((ext_vector_type(4))) float floatx4;

__device__ __forceinline__ ushort f2b(float f) {   // fp32 -> bf16 RNE
    union { float f; unsigned u; } v; v.f = f;
    unsigned r = v.u + 0x7FFFu + ((v.u >> 16) & 1u);
    return (ushort)(r >> 16);
}

__global__ __launch_bounds__(256) void bucket_hist_kernel(const int* __restrict__ dsts,
                                                          int* __restrict__ bdeg,
                                                          int E, int B) {
    __shared__ int h[BMAX];
    for (int i = threadIdx.x; i < B; i += 256) h[i] = 0;
    __syncthreads();
    for (int e = blockIdx.x * 256 + threadIdx.x; e < E; e += gridDim.x * 256)
        atomicAdd(&h[((unsigned)dsts[e]) >> SHIFT], 1);
    __syncthreads();
    for (int i = threadIdx.x; i < B; i += 256)
        if (h[i]) atomicAdd(&bdeg[i], h[i]);
}

__global__ __launch_bounds__(512) void bucket_prefix_kernel(const int* __restrict__ bdeg,
                                                            int* __restrict__ bbase,
                                                            int* __restrict__ bcur, int B) {
    __shared__ int sv[BMAX];
    int tid = threadIdx.x;
    int v = (tid < B) ? bdeg[tid] : 0;
    sv[tid] = v;
    __syncthreads();
    for (int off = 1; off < BMAX; off <<= 1) {
        int t = (tid >= off) ? sv[tid - off] : 0;
        __syncthreads();
        sv[tid] += t;
        __syncthreads();
    }
    int excl = sv[tid] - v;
    if (tid < B) { bbase[tid] = excl; bcur[tid] = excl; }
}

// tile of 8192 edges: LDS histogram -> one global cursor atomic per
// (block,bucket) -> packed (dstLocal<<17 | src) written in ~21-entry runs
__global__ __launch_bounds__(256) void binning_kernel(const int* __restrict__ srcs,
                                                      const int* __restrict__ dsts,
                                                      int* __restrict__ bcur,
                                                      int* __restrict__ staging,
                                                      int E, int B) {
    __shared__ int h[BMAX];
    __shared__ int cur[BMAX];
    int tile0 = blockIdx.x * TILE;
    for (int i = threadIdx.x; i < B; i += 256) h[i] = 0;
    __syncthreads();
#pragma unroll 4
    for (int j = 0; j < EPT; ++j) {
        int e = tile0 + j * 256 + threadIdx.x;
        if (e < E) atomicAdd(&h[((unsigned)dsts[e]) >> SHIFT], 1);
    }
    __syncthreads();
    for (int i = threadIdx.x; i < B; i += 256)
        cur[i] = h[i] ? atomicAdd(&bcur[i], h[i]) : 0;
    __syncthreads();
#pragma unroll 4
    for (int j = 0; j < EPT; ++j) {
        int e = tile0 + j * 256 + threadIdx.x;
        if (e < E) {
            int d = dsts[e], s = srcs[e];
            int b = ((unsigned)d) >> SHIFT;
            int pos = atomicAdd(&cur[b], 1);
            staging[pos] = ((d & (NPB - 1)) << 17) | s;
        }
    }
}

// one block (512 thr) per bucket: per-node LDS histogram + scan ->
// start/deg/dinv, then scatter srcs inside the bucket's private csr window
__global__ __launch_bounds__(512) void finalize_kernel(const int* __restrict__ staging,
                                                       const int* __restrict__ bdeg,
                                                       const int* __restrict__ bbase,
                                                       int* __restrict__ csr,
                                                       int* __restrict__ deg,
                                                       int* __restrict__ start,
                                                       float* __restrict__ dinv, int n) {
    int b = blockIdx.x;
    int base = bbase[b], count = bdeg[b];
    __shared__ int nd[NPB];
    __shared__ int sv[NPB];
    __shared__ int ncur[NPB];
    int tid = threadIdx.x;
    if (tid < NPB) nd[tid] = 0;
    __syncthreads();
    for (int i = tid; i < count; i += 512)
        atomicAdd(&nd[staging[base + i] >> 17], 1);
    __syncthreads();
    int d0 = 0;
    if (tid < NPB) { d0 = nd[tid]; sv[tid] = d0; }
    __syncthreads();
    for (int off = 1; off < NPB; off <<= 1) {
        int t = 0;
        if (tid < NPB && tid >= off) t = sv[tid - off];
        __syncthreads();
        if (tid < NPB) sv[tid] += t;
        __syncthreads();
    }
    if (tid < NPB) {
        int excl = sv[tid] - d0;
        ncur[tid] = excl;
        int node = (b << SHIFT) + tid;
        if (node < n) {
            start[node] = base + excl;
            deg[node] = d0;
            dinv[node] = rsqrtf((float)d0 + 1.0f);
        }
    }
    __syncthreads();
    for (int i = tid; i < count; i += 512) {
        int p = staging[base + i];
        int pos = atomicAdd(&ncur[p >> 17], 1);
        csr[base + pos] = p & 0x1FFFF;
    }
}

// xs[s][c] = fp16( x[s][c] * dinv[s] ) — one thread per 4 channels
__global__ __launch_bounds__(256) void xs_kernel(const float* __restrict__ x,
                                                 const float* __restrict__ dinv,
                                                 __half* __restrict__ xs, int total) {
    int i = blockIdx.x * 256 + threadIdx.x;   // over n*16 float4 groups
    if (i >= total) return;
    float dn = dinv[i >> 4];
    float4 v = ((const float4*)x)[i];
    __half2 a = __floats2half2_rn(v.x * dn, v.y * dn);
    __half2 b = __floats2half2_rn(v.z * dn, v.w * dn);
    ((__half2*)xs)[i * 2 + 0] = a;
    ((__half2*)xs)[i * 2 + 1] = b;
}

// one wave per node. Lane = (edge_group 0..7) x (chunk 0..7). Per 64-edge
// chunk: ONE coalesced csr load (indices distributed via shfl), row loop 2x
// unrolled with weight-predication so two 16B row loads are in flight.
__global__ __launch_bounds__(256) void gather_kernel(const int* __restrict__ csr,
                                                     const int* __restrict__ start,
                                                     const int* __restrict__ deg,
                                                     const __half* __restrict__ xs,
                                                     const float* __restrict__ dinv,
                                                     ushort* __restrict__ aggb, int n) {
    int wave = threadIdx.x >> 6;
    int lane = threadIdx.x & 63;
    int node = blockIdx.x * 4 + wave;
    if (node >= n) return;
    int eg = lane >> 3;      // edge group 0..7
    int c  = lane & 7;       // 16B chunk (8 halfs)
    int s0 = start[node];
    int d  = deg[node];
    float acc[8] = {0.f, 0.f, 0.f, 0.f, 0.f, 0.f, 0.f, 0.f};
    for (int chunk = 0; chunk < d; chunk += 64) {
        int nrem = d - chunk;
        if (nrem > 64) nrem = 64;
        int ml = lane < nrem ? lane : nrem - 1;
        int idx = csr[s0 + chunk + ml];          // one coalesced load / chunk
        for (int base = 0; base < nrem; base += 16) {
            int e0 = base + eg;
            int e1 = base + 8 + eg;
            int i0 = __shfl(idx, e0 < nrem ? e0 : nrem - 1);
            int i1 = __shfl(idx, e1 < nrem ? e1 : nrem - 1);
            float w0 = e0 < nrem ? 1.0f : 0.0f;
            float w1 = e1 < nrem ? 1.0f : 0.0f;
            union { uint4 u; __half2 h[4]; } p0, p1;
            p0.u = *(const uint4*)(xs + (size_t)i0 * 64 + c * 8);
            p1.u = *(const uint4*)(xs + (size_t)i1 * 64 + c * 8);
#pragma unroll
            for (int t = 0; t < 4; ++t) {
                float2 f = __half22float2(p0.h[t]);
                acc[2 * t + 0] = fmaf(f.x, w0, acc[2 * t + 0]);
                acc[2 * t + 1] = fmaf(f.y, w0, acc[2 * t + 1]);
            }
#pragma unroll
            for (int t = 0; t < 4; ++t) {
                float2 f = __half22float2(p1.h[t]);
                acc[2 * t + 0] = fmaf(f.x, w1, acc[2 * t + 0]);
                acc[2 * t + 1] = fmaf(f.y, w1, acc[2 * t + 1]);
            }
        }
    }
#pragma unroll
    for (int off = 32; off >= 8; off >>= 1) {
#pragma unroll
        for (int t = 0; t < 8; ++t) acc[t] += __shfl_down(acc[t], off);
    }
    if (eg == 0) {
        float dn = dinv[node];
        union { uint4 u; __half2 h[4]; } p;
        p.u = *(const uint4*)(xs + (size_t)node * 64 + c * 8);
        uint4 o;
        unsigned* ow = (unsigned*)&o;
#pragma unroll
        for (int t = 0; t < 4; ++t) {
            float2 f = __half22float2(p.h[t]);
            float v0 = dn * fmaf(f.x, dn, acc[2 * t + 0]);
            float v1 = dn * fmaf(f.y, dn, acc[2 * t + 1]);
            ow[t] = (unsigned)f2b(v0) | ((unsigned)f2b(v1) << 16);
        }
        ((uint4*)(aggb + (size_t)node * 64))[c] = o;
    }
}

// Mb[j][k] = bf16( sum_t W[k][t] * L[t][j] ), j in [0,512): j<256 z, else h.
// Row-major [512][64] bf16 == MFMA B-operand order. cb[j] = bias fold.
__global__ __launch_bounds__(64) void build_m_kernel(
    const float* __restrict__ Wz, const float* __restrict__ bz,
    const float* __restrict__ Wh, const float* __restrict__ bh,
    const float* __restrict__ Lzw, const float* __restrict__ Lzb,
    const float* __restrict__ Lhw, const float* __restrict__ Lhb,
    ushort* __restrict__ Mb, float* __restrict__ cb) {
    int j = blockIdx.x;          // 0..511
    int k = threadIdx.x;         // 0..63
    int which = j >> 8;
    int jj = j & 255;
    const float* W  = which ? Wh  : Wz;
    const float* bv = which ? bh  : bz;
    const float* L  = which ? Lhw : Lzw;   // [512,256]; rows 0..255 only (H0=0)
    const float* Lb = which ? Lhb : Lzb;
    float acc = 0.f;
    for (int t = 0; t < 256; ++t) acc = fmaf(W[k * 256 + t], L[t * 256 + jj], acc);
    Mb[j * 64 + k] = f2b(acc);
    if (k == 0) {
        float a = 0.f;
        for (int t = 0; t < 256; ++t) a = fmaf(bv[t], L[t * 256 + jj], a);
        cb[j] = a + Lb[jj];
    }
}

// 512 threads = 8 waves. Wave w owns cols w*32..w*32+31 for BOTH gates:
// z and ht for a channel meet in-register, h=relu((1-z)*ht) computed in the
// epilogue, only ONE 16.6KB h-plane goes through LDS (R10 stored z+ht planes,
// 32KB). Per 16-node tile per wave: 2 A-frag loads + 8 MFMA (unchanged).
__global__ __launch_bounds__(512) void node_mfma_kernel(
    const ushort* __restrict__ aggb,   // [n][64] bf16
    const ushort* __restrict__ Mb,     // [512][64] bf16 (B layout)
    const float* __restrict__ cb,      // [512]
    const float* __restrict__ Wo, const float* __restrict__ bo,
    float* __restrict__ out, int n) {
    int tid  = threadIdx.x;
    int w    = tid >> 6;
    int lane = tid & 63;
    int nidx = lane & 15;
    int quad = lane >> 4;
    short8 bfz[2][2], bfh[2][2];
    float cbz[2], cbh[2];
#pragma unroll
    for (int cg = 0; cg < 2; ++cg) {
        int colZ = (w << 5) + (cg << 4) + nidx;
        int colH = 256 + colZ;
#pragma unroll
        for (int s = 0; s < 2; ++s) {
            bfz[cg][s] = *(const short8*)(Mb + colZ * 64 + s * 32 + quad * 8);
            bfh[cg][s] = *(const short8*)(Mb + colH * 64 + s * 32 + quad * 8);
        }
        cbz[cg] = cb[colZ];
        cbh[cg] = cb[colH];
    }
    __shared__ float sH[16][260];    // 16.6 KB h-plane (pad 260: 2-way alias)
    __shared__ float sWo[4][256];
    if (tid < 256) {
#pragma unroll
        for (int o = 0; o < 4; ++o) sWo[o][tid] = Wo[tid * 4 + o];
    }
    float bo0 = bo[0], bo1 = bo[1], bo2 = bo[2], bo3 = bo[3];
    int ntiles = (n + 15) >> 4;
    for (int tile = blockIdx.x; tile < ntiles; tile += gridDim.x) {
        int node0 = tile << 4;
        int nodeA = node0 + nidx;
        if (nodeA >= n) nodeA = n - 1;   // clamp; stores are guarded
        const ushort* arow = aggb + (size_t)nodeA * 64;
        short8 a0 = *(const short8*)(arow + quad * 8);
        short8 a1 = *(const short8*)(arow + 32 + quad * 8);
#pragma unroll
        for (int cg = 0; cg < 2; ++cg) {
            floatx4 cz = {cbz[cg], cbz[cg], cbz[cg], cbz[cg]};
            cz = __builtin_amdgcn_mfma_f32_16x16x32_bf16(a0, bfz[cg][0], cz, 0, 0, 0);
            cz = __builtin_amdgcn_mfma_f32_16x16x32_bf16(a1, bfz[cg][1], cz, 0, 0, 0);
            floatx4 chh = {cbh[cg], cbh[cg], cbh[cg], cbh[cg]};
            chh = __builtin_amdgcn_mfma_f32_16x16x32_bf16(a0, bfh[cg][0], chh, 0, 0, 0);
            chh = __builtin_amdgcn_mfma_f32_16x16x32_bf16(a1, bfh[cg][1], chh, 0, 0, 0);
            int col = (w << 5) + (cg << 4) + nidx;
#pragma unroll
            for (int r = 0; r < 4; ++r) {
                int row = (quad << 2) + r;                   // node within tile
                float zc = 1.0f / (1.0f + __expf(cz[r]));    // 1 - sigmoid
                float th = 1.0f - 2.0f / (1.0f + __expf(2.0f * chh[r]));
                sH[row][col] = fmaxf(zc * th, 0.0f);
            }
        }
        __syncthreads();
        {   // head: 32 threads per node, 8 channels each
            int nb = tid >> 5, g = tid & 31;
            float l0 = 0.f, l1 = 0.f, l2 = 0.f, l3 = 0.f;
#pragma unroll
            for (int ii = 0; ii < 8; ++ii) {
                int ch = g + 32 * ii;
                float hv = sH[nb][ch];
                l0 = fmaf(hv, sWo[0][ch], l0);
                l1 = fmaf(hv, sWo[1][ch], l1);
                l2 = fmaf(hv, sWo[2][ch], l2);
                l3 = fmaf(hv, sWo[3][ch], l3);
            }
#pragma unroll
            for (int off = 16; off > 0; off >>= 1) {
                l0 += __shfl_down(l0, off, 32);
                l1 += __shfl_down(l1, off, 32);
                l2 += __shfl_down(l2, off, 32);
                l3 += __shfl_down(l3, off, 32);
            }
            int node = node0 + nb;
            if (g == 0 && node < n) {
                float v0 = l0 + bo0, v1 = l1 + bo1, v2 = l2 + bo2, v3 = l3 + bo3;
                float mx = fmaxf(fmaxf(v0, v1), fmaxf(v2, v3));
                float e0 = __expf(v0 - mx), e1 = __expf(v1 - mx);
                float e2 = __expf(v2 - mx), e3 = __expf(v3 - mx);
                float inv = 1.0f / (e0 + e1 + e2 + e3);
                float4 o;
                o.x = e0 * inv; o.y = e1 * inv; o.z = e2 * inv; o.w = e3 * inv;
                ((float4*)out)[node] = o;
            }
        }
        __syncthreads();
    }
}

extern "C" void kernel_launch(void* const* d_in, const int* in_sizes, int n_in,
                              void* d_out, int out_size, void* d_ws, size_t ws_size,
                              hipStream_t stream) {
    const float* x   = (const float*)d_in[0];
    const int*  eidx = (const int*)d_in[1];
    const float* Wz  = (const float*)d_in[2];
    const float* bz  = (const float*)d_in[3];
    // d_in[4]=Wr, d_in[5]=br : dead (H0 = 0)
    const float* Wh  = (const float*)d_in[6];
    const float* bh  = (const float*)d_in[7];
    const float* Lzw = (const float*)d_in[8];
    const float* Lzb = (const float*)d_in[9];
    // d_in[10]=Lrw, d_in[11]=Lrb : dead
    const float* Lhw = (const float*)d_in[12];
    const float* Lhb = (const float*)d_in[13];
    const float* Wo  = (const float*)d_in[14];
    const float* bo  = (const float*)d_in[15];
    float* out = (float*)d_out;

    int n = in_sizes[0] / 64;
    int E = in_sizes[1] / 2;
    const int* srcs = eidx;
    const int* dsts = eidx + E;
    int B = (n + NPB - 1) >> SHIFT;

    size_t na = ((size_t)n + 3) & ~(size_t)3;
    size_t aggBytes = (size_t)n * 64 * 2;                 // bf16 agg
    size_t stageBytes = (size_t)E * 4 + 16;               // staging (aliases agg)
    size_t bigBytes = (aggBytes > stageBytes ? aggBytes : stageBytes);
    bigBytes = (bigBytes + 255) & ~(size_t)255;

    char* ws = (char*)d_ws;
    int*   deg   = (int*)ws;    ws += na * 4;
    int*   start = (int*)ws;    ws += na * 4;
    float* dinv  = (float*)ws;  ws += na * 4;
    int*   bdeg  = (int*)ws;    ws += BMAX * 4;
    int*   bbase = (int*)ws;    ws += BMAX * 4;
    int*   bcur  = (int*)ws;    ws += BMAX * 4;
    int*   csr   = (int*)ws;    ws += (size_t)E * 4;
    __half* xs   = (__half*)ws; ws += (size_t)n * 64 * 2;
    ushort* aggb = (ushort*)ws;
    int*   staging = (int*)aggb;   // aliases aggb: staging dead before gather
    ws += bigBytes;
    ushort* Mb   = (ushort*)ws; ws += 512 * 64 * 2;
    float* cb    = (float*)ws;  ws += 512 * 4;

    hipMemsetAsync(bdeg, 0, BMAX * sizeof(int), stream);

    bucket_hist_kernel<<<1024, 256, 0, stream>>>(dsts, bdeg, E, B);
    bucket_prefix_kernel<<<1, BMAX, 0, stream>>>(bdeg, bbase, bcur, B);
    binning_kernel<<<(E + TILE - 1) / TILE, 256, 0, stream>>>(srcs, dsts, bcur,
                                                              staging, E, B);
    finalize_kernel<<<B, 512, 0, stream>>>(staging, bdeg, bbase, csr, deg, start,
                                           dinv, n);
    build_m_kernel<<<512, 64, 0, stream>>>(Wz, bz, Wh, bh, Lzw, Lzb, Lhw, Lhb,
                                           Mb, cb);
    xs_kernel<<<(n * 16 + 255) / 256, 256, 0, stream>>>(x, dinv, xs, n * 16);
    gather_kernel<<<(n + 3) / 4, 256, 0, stream>>>(csr, start, deg, xs, dinv,
                                                   aggb, n);
    node_mfma_kernel<<<2048, 512, 0, stream>>>(aggb, Mb, cb, Wo, bo, out, n);
}

// Round 12
// 309.517 us; speedup vs baseline: 2.3795x; 1.0352x over previous
//
#include <hip/hip_runtime.h>
#include <hip/hip_fp16.h>

// TGCN forward, algebraically reduced (H0 = 0 => R/Wr dead, Z*H = 0):
//   deg[d] = #in-edges of d ; dinv = rsqrt(deg+1)
//   xs[s]  = fp16( x[s] * dinv[s] )
//   agg[d] = bf16( dinv[d] * ( sum_{e: dst=d} xs[src] + xs[d]*dinv[d] ) )
//   M = [Wz@Lzw_top | Wh@Lhw_top]  (64x512, bf16, MFMA B-layout), cb = bias fold
//   out = softmax(relu((1-Z)*Ht) @ Wo + bo), Z/Ht from agg@M via MFMA
//
// R1 -> R2: atomic scatter (2700us) -> CSR build + register gather.
// R3 -> R4: scatter 16x write amp -> 2-level bucket sort (793 -> 455us).
// R4 -> R7: register-allocator fights over 64-float M column — dead end.
// R7 -> R8: node GEMM -> mfma_f32_16x16x32_bf16 (412 -> off top-5).
// R8 -> R9: xs = fp16(x*dinv): row 256B -> 128B (gather 124 -> 75).
// R10 -> R11: binning TILE 8192 (write amp 6x -> 3x), node_mfma single
// h-plane. Both helped less than predicted: binning is OCCUPANCY-bound
// (13%, 391 blocks x 4 waves; VALUBusy 2%), node_mfma barrier/entry-bound.
// R11 -> R12: binning 512 thr/block (12 waves/CU, same traffic — WRITE_SIZE
// should stay ~43MB while dur ~halves). node_mfma 32-node tiles (16 MFMA
// between barriers), 1024-block co-resident grid, 16-thr/node head.

#define SHIFT 8
#define NPB   256          // nodes per bucket (=1<<SHIFT)
#define BMAX  512          // max buckets (n <= 131072 for 17-bit src packing)
#define TILE  8192         // edges per binning block

typedef __attribute__((ext_vector_type(8))) short short8;
typedef __attribute__((ext_vector_type(4))) float floatx4;

__device__ __forceinline__ ushort f2b(float f) {   // fp32 -> bf16 RNE
    union { float f; unsigned u; } v; v.f = f;
    unsigned r = v.u + 0x7FFFu + ((v.u >> 16) & 1u);
    return (ushort)(r >> 16);
}

__global__ __launch_bounds__(256) void bucket_hist_kernel(const int* __restrict__ dsts,
                                                          int* __restrict__ bdeg,
                                                          int E, int B) {
    __shared__ int h[BMAX];
    for (int i = threadIdx.x; i < B; i += 256) h[i] = 0;
    __syncthreads();
    for (int e = blockIdx.x * 256 + threadIdx.x; e < E; e += gridDim.x * 256)
        atomicAdd(&h[((unsigned)dsts[e]) >> SHIFT], 1);
    __syncthreads();
    for (int i = threadIdx.x; i < B; i += 256)
        if (h[i]) atomicAdd(&bdeg[i], h[i]);
}

__global__ __launch_bounds__(512) void bucket_prefix_kernel(const int* __restrict__ bdeg,
                                                            int* __restrict__ bbase,
                                                            int* __restrict__ bcur, int B) {
    __shared__ int sv[BMAX];
    int tid = threadIdx.x;
    int v = (tid < B) ? bdeg[tid] : 0;
    sv[tid] = v;
    __syncthreads();
    for (int off = 1; off < BMAX; off <<= 1) {
        int t = (tid >= off) ? sv[tid - off] : 0;
        __syncthreads();
        sv[tid] += t;
        __syncthreads();
    }
    int excl = sv[tid] - v;
    if (tid < B) { bbase[tid] = excl; bcur[tid] = excl; }
}

// tile of 8192 edges, 512 threads (R12: was 256 — occupancy 13% was the
// limiter, not traffic): LDS histogram -> one global cursor atomic per
// (block,bucket) -> packed (dstLocal<<17 | src) written in ~21-entry runs
__global__ __launch_bounds__(512) void binning_kernel(const int* __restrict__ srcs,
                                                      const int* __restrict__ dsts,
                                                      int* __restrict__ bcur,
                                                      int* __restrict__ staging,
                                                      int E, int B) {
    __shared__ int h[BMAX];
    __shared__ int cur[BMAX];
    int tile0 = blockIdx.x * TILE;
    for (int i = threadIdx.x; i < B; i += 512) h[i] = 0;
    __syncthreads();
#pragma unroll 4
    for (int j = 0; j < TILE / 512; ++j) {
        int e = tile0 + j * 512 + threadIdx.x;
        if (e < E) atomicAdd(&h[((unsigned)dsts[e]) >> SHIFT], 1);
    }
    __syncthreads();
    for (int i = threadIdx.x; i < B; i += 512)
        cur[i] = h[i] ? atomicAdd(&bcur[i], h[i]) : 0;
    __syncthreads();
#pragma unroll 4
    for (int j = 0; j < TILE / 512; ++j) {
        int e = tile0 + j * 512 + threadIdx.x;
        if (e < E) {
            int d = dsts[e], s = srcs[e];
            int b = ((unsigned)d) >> SHIFT;
            int pos = atomicAdd(&cur[b], 1);
            staging[pos] = ((d & (NPB - 1)) << 17) | s;
        }
    }
}

// one block (512 thr) per bucket: per-node LDS histogram + scan ->
// start/deg/dinv, then scatter srcs inside the bucket's private csr window
__global__ __launch_bounds__(512) void finalize_kernel(const int* __restrict__ staging,
                                                       const int* __restrict__ bdeg,
                                                       const int* __restrict__ bbase,
                                                       int* __restrict__ csr,
                                                       int* __restrict__ deg,
                                                       int* __restrict__ start,
                                                       float* __restrict__ dinv, int n) {
    int b = blockIdx.x;
    int base = bbase[b], count = bdeg[b];
    __shared__ int nd[NPB];
    __shared__ int sv[NPB];
    __shared__ int ncur[NPB];
    int tid = threadIdx.x;
    if (tid < NPB) nd[tid] = 0;
    __syncthreads();
    for (int i = tid; i < count; i += 512)
        atomicAdd(&nd[staging[base + i] >> 17], 1);
    __syncthreads();
    int d0 = 0;
    if (tid < NPB) { d0 = nd[tid]; sv[tid] = d0; }
    __syncthreads();
    for (int off = 1; off < NPB; off <<= 1) {
        int t = 0;
        if (tid < NPB && tid >= off) t = sv[tid - off];
        __syncthreads();
        if (tid < NPB) sv[tid] += t;
        __syncthreads();
    }
    if (tid < NPB) {
        int excl = sv[tid] - d0;
        ncur[tid] = excl;
        int node = (b << SHIFT) + tid;
        if (node < n) {
            start[node] = base + excl;
            deg[node] = d0;
            dinv[node] = rsqrtf((float)d0 + 1.0f);
        }
    }
    __syncthreads();
    for (int i = tid; i < count; i += 512) {
        int p = staging[base + i];
        int pos = atomicAdd(&ncur[p >> 17], 1);
        csr[base + pos] = p & 0x1FFFF;
    }
}

// xs[s][c] = fp16( x[s][c] * dinv[s] ) — one thread per 4 channels
__global__ __launch_bounds__(256) void xs_kernel(const float* __restrict__ x,
                                                 const float* __restrict__ dinv,
                                                 __half* __restrict__ xs, int total) {
    int i = blockIdx.x * 256 + threadIdx.x;   // over n*16 float4 groups
    if (i >= total) return;
    float dn = dinv[i >> 4];
    float4 v = ((const float4*)x)[i];
    __half2 a = __floats2half2_rn(v.x * dn, v.y * dn);
    __half2 b = __floats2half2_rn(v.z * dn, v.w * dn);
    ((__half2*)xs)[i * 2 + 0] = a;
    ((__half2*)xs)[i * 2 + 1] = b;
}

// one wave per node. Lane = (edge_group 0..7) x (chunk 0..7). Per 64-edge
// chunk: ONE coalesced csr load (indices distributed via shfl), row loop 2x
// unrolled with weight-predication so two 16B row loads are in flight.
__global__ __launch_bounds__(256) void gather_kernel(const int* __restrict__ csr,
                                                     const int* __restrict__ start,
                                                     const int* __restrict__ deg,
                                                     const __half* __restrict__ xs,
                                                     const float* __restrict__ dinv,
                                                     ushort* __restrict__ aggb, int n) {
    int wave = threadIdx.x >> 6;
    int lane = threadIdx.x & 63;
    int node = blockIdx.x * 4 + wave;
    if (node >= n) return;
    int eg = lane >> 3;      // edge group 0..7
    int c  = lane & 7;       // 16B chunk (8 halfs)
    int s0 = start[node];
    int d  = deg[node];
    float acc[8] = {0.f, 0.f, 0.f, 0.f, 0.f, 0.f, 0.f, 0.f};
    for (int chunk = 0; chunk < d; chunk += 64) {
        int nrem = d - chunk;
        if (nrem > 64) nrem = 64;
        int ml = lane < nrem ? lane : nrem - 1;
        int idx = csr[s0 + chunk + ml];          // one coalesced load / chunk
        for (int base = 0; base < nrem; base += 16) {
            int e0 = base + eg;
            int e1 = base + 8 + eg;
            int i0 = __shfl(idx, e0 < nrem ? e0 : nrem - 1);
            int i1 = __shfl(idx, e1 < nrem ? e1 : nrem - 1);
            float w0 = e0 < nrem ? 1.0f : 0.0f;
            float w1 = e1 < nrem ? 1.0f : 0.0f;
            union { uint4 u; __half2 h[4]; } p0, p1;
            p0.u = *(const uint4*)(xs + (size_t)i0 * 64 + c * 8);
            p1.u = *(const uint4*)(xs + (size_t)i1 * 64 + c * 8);
#pragma unroll
            for (int t = 0; t < 4; ++t) {
                float2 f = __half22float2(p0.h[t]);
                acc[2 * t + 0] = fmaf(f.x, w0, acc[2 * t + 0]);
                acc[2 * t + 1] = fmaf(f.y, w0, acc[2 * t + 1]);
            }
#pragma unroll
            for (int t = 0; t < 4; ++t) {
                float2 f = __half22float2(p1.h[t]);
                acc[2 * t + 0] = fmaf(f.x, w1, acc[2 * t + 0]);
                acc[2 * t + 1] = fmaf(f.y, w1, acc[2 * t + 1]);
            }
        }
    }
#pragma unroll
    for (int off = 32; off >= 8; off >>= 1) {
#pragma unroll
        for (int t = 0; t < 8; ++t) acc[t] += __shfl_down(acc[t], off);
    }
    if (eg == 0) {
        float dn = dinv[node];
        union { uint4 u; __half2 h[4]; } p;
        p.u = *(const uint4*)(xs + (size_t)node * 64 + c * 8);
        uint4 o;
        unsigned* ow = (unsigned*)&o;
#pragma unroll
        for (int t = 0; t < 4; ++t) {
            float2 f = __half22float2(p.h[t]);
            float v0 = dn * fmaf(f.x, dn, acc[2 * t + 0]);
            float v1 = dn * fmaf(f.y, dn, acc[2 * t + 1]);
            ow[t] = (unsigned)f2b(v0) | ((unsigned)f2b(v1) << 16);
        }
        ((uint4*)(aggb + (size_t)node * 64))[c] = o;
    }
}

// Mb[j][k] = bf16( sum_t W[k][t] * L[t][j] ), j in [0,512): j<256 z, else h.
// Row-major [512][64] bf16 == MFMA B-operand order. cb[j] = bias fold.
__global__ __launch_bounds__(64) void build_m_kernel(
    const float* __restrict__ Wz, const float* __restrict__ bz,
    const float* __restrict__ Wh, const float* __restrict__ bh,
    const float* __restrict__ Lzw, const float* __restrict__ Lzb,
    const float* __restrict__ Lhw, const float* __restrict__ Lhb,
    ushort* __restrict__ Mb, float* __restrict__ cb) {
    int j = blockIdx.x;          // 0..511
    int k = threadIdx.x;         // 0..63
    int which = j >> 8;
    int jj = j & 255;
    const float* W  = which ? Wh  : Wz;
    const float* bv = which ? bh  : bz;
    const float* L  = which ? Lhw : Lzw;   // [512,256]; rows 0..255 only (H0=0)
    const float* Lb = which ? Lhb : Lzb;
    float acc = 0.f;
    for (int t = 0; t < 256; ++t) acc = fmaf(W[k * 256 + t], L[t * 256 + jj], acc);
    Mb[j * 64 + k] = f2b(acc);
    if (k == 0) {
        float a = 0.f;
        for (int t = 0; t < 256; ++t) a = fmaf(bv[t], L[t * 256 + jj], a);
        cb[j] = a + Lb[jj];
    }
}

// 512 threads = 8 waves. Wave w owns cols w*32..w*32+31 for BOTH gates
// (z and ht meet in-register, h=relu((1-z)*ht) -> one h-plane in LDS).
// R12: 32-node tiles — 16 MFMA between barriers (2x R11), head 16 thr/node,
// grid 1024 co-resident so b-frag entry loads are paid once per block.
__global__ __launch_bounds__(512) void node_mfma_kernel(
    const ushort* __restrict__ aggb,   // [n][64] bf16
    const ushort* __restrict__ Mb,     // [512][64] bf16 (B layout)
    const float* __restrict__ cb,      // [512]
    const float* __restrict__ Wo, const float* __restrict__ bo,
    float* __restrict__ out, int n) {
    int tid  = threadIdx.x;
    int w    = tid >> 6;
    int lane = tid & 63;
    int nidx = lane & 15;
    int quad = lane >> 4;
    short8 bfz[2][2], bfh[2][2];
    float cbz[2], cbh[2];
#pragma unroll
    for (int cg = 0; cg < 2; ++cg) {
        int colZ = (w << 5) + (cg << 4) + nidx;
        int colH = 256 + colZ;
#pragma unroll
        for (int s = 0; s < 2; ++s) {
            bfz[cg][s] = *(const short8*)(Mb + colZ * 64 + s * 32 + quad * 8);
            bfh[cg][s] = *(const short8*)(Mb + colH * 64 + s * 32 + quad * 8);
        }
        cbz[cg] = cb[colZ];
        cbh[cg] = cb[colH];
    }
    __shared__ float sH[32][260];    // 33 KB h-plane (260 pad: 2-way on stores)
    __shared__ float sWo[4][256];
    if (tid < 256) {
#pragma unroll
        for (int o = 0; o < 4; ++o) sWo[o][tid] = Wo[tid * 4 + o];
    }
    float bo0 = bo[0], bo1 = bo[1], bo2 = bo[2], bo3 = bo[3];
    int ntiles = (n + 31) >> 5;
    for (int tile = blockIdx.x; tile < ntiles; tile += gridDim.x) {
        int node0 = tile << 5;
        int nA0 = node0 + nidx;
        int nA1 = node0 + 16 + nidx;
        if (nA0 >= n) nA0 = n - 1;   // clamp; stores are guarded
        if (nA1 >= n) nA1 = n - 1;
        const ushort* ar0 = aggb + (size_t)nA0 * 64;
        const ushort* ar1 = aggb + (size_t)nA1 * 64;
        short8 a00 = *(const short8*)(ar0 + quad * 8);
        short8 a01 = *(const short8*)(ar0 + 32 + quad * 8);
        short8 a10 = *(const short8*)(ar1 + quad * 8);
        short8 a11 = *(const short8*)(ar1 + 32 + quad * 8);
#pragma unroll
        for (int cg = 0; cg < 2; ++cg) {
            int col = (w << 5) + (cg << 4) + nidx;
#pragma unroll
            for (int grp = 0; grp < 2; ++grp) {
                short8 a0 = grp ? a10 : a00;
                short8 a1 = grp ? a11 : a01;
                floatx4 cz = {cbz[cg], cbz[cg], cbz[cg], cbz[cg]};
                cz = __builtin_amdgcn_mfma_f32_16x16x32_bf16(a0, bfz[cg][0], cz, 0, 0, 0);
                cz = __builtin_amdgcn_mfma_f32_16x16x32_bf16(a1, bfz[cg][1], cz, 0, 0, 0);
                floatx4 chh = {cbh[cg], cbh[cg], cbh[cg], cbh[cg]};
                chh = __builtin_amdgcn_mfma_f32_16x16x32_bf16(a0, bfh[cg][0], chh, 0, 0, 0);
                chh = __builtin_amdgcn_mfma_f32_16x16x32_bf16(a1, bfh[cg][1], chh, 0, 0, 0);
#pragma unroll
                for (int r = 0; r < 4; ++r) {
                    int row = (grp << 4) + (quad << 2) + r;   // node within tile
                    float zc = 1.0f / (1.0f + __expf(cz[r]));    // 1 - sigmoid
                    float th = 1.0f - 2.0f / (1.0f + __expf(2.0f * chh[r]));
                    sH[row][col] = fmaxf(zc * th, 0.0f);
                }
            }
        }
        __syncthreads();
        {   // head: 16 threads per node, 16 channels each
            int nb = tid >> 4, g = tid & 15;
            float l0 = 0.f, l1 = 0.f, l2 = 0.f, l3 = 0.f;
#pragma unroll
            for (int ii = 0; ii < 16; ++ii) {
                int ch = g + 16 * ii;
                float hv = sH[nb][ch];
                l0 = fmaf(hv, sWo[0][ch], l0);
                l1 = fmaf(hv, sWo[1][ch], l1);
                l2 = fmaf(hv, sWo[2][ch], l2);
                l3 = fmaf(hv, sWo[3][ch], l3);
            }
#pragma unroll
            for (int off = 8; off > 0; off >>= 1) {
                l0 += __shfl_down(l0, off, 16);
                l1 += __shfl_down(l1, off, 16);
                l2 += __shfl_down(l2, off, 16);
                l3 += __shfl_down(l3, off, 16);
            }
            int node = node0 + nb;
            if (g == 0 && node < n) {
                float v0 = l0 + bo0, v1 = l1 + bo1, v2 = l2 + bo2, v3 = l3 + bo3;
                float mx = fmaxf(fmaxf(v0, v1), fmaxf(v2, v3));
                float e0 = __expf(v0 - mx), e1 = __expf(v1 - mx);
                float e2 = __expf(v2 - mx), e3 = __expf(v3 - mx);
                float inv = 1.0f / (e0 + e1 + e2 + e3);
                float4 o;
                o.x = e0 * inv; o.y = e1 * inv; o.z = e2 * inv; o.w = e3 * inv;
                ((float4*)out)[node] = o;
            }
        }
        __syncthreads();
    }
}

extern "C" void kernel_launch(void* const* d_in, const int* in_sizes, int n_in,
                              void* d_out, int out_size, void* d_ws, size_t ws_size,
                              hipStream_t stream) {
    const float* x   = (const float*)d_in[0];
    const int*  eidx = (const int*)d_in[1];
    const float* Wz  = (const float*)d_in[2];
    const float* bz  = (const float*)d_in[3];
    // d_in[4]=Wr, d_in[5]=br : dead (H0 = 0)
    const float* Wh  = (const float*)d_in[6];
    const float* bh  = (const float*)d_in[7];
    const float* Lzw = (const float*)d_in[8];
    const float* Lzb = (const float*)d_in[9];
    // d_in[10]=Lrw, d_in[11]=Lrb : dead
    const float* Lhw = (const float*)d_in[12];
    const float* Lhb = (const float*)d_in[13];
    const float* Wo  = (const float*)d_in[14];
    const float* bo  = (const float*)d_in[15];
    float* out = (float*)d_out;

    int n = in_sizes[0] / 64;
    int E = in_sizes[1] / 2;
    const int* srcs = eidx;
    const int* dsts = eidx + E;
    int B = (n + NPB - 1) >> SHIFT;

    size_t na = ((size_t)n + 3) & ~(size_t)3;
    size_t aggBytes = (size_t)n * 64 * 2;                 // bf16 agg
    size_t stageBytes = (size_t)E * 4 + 16;               // staging (aliases agg)
    size_t bigBytes = (aggBytes > stageBytes ? aggBytes : stageBytes);
    bigBytes = (bigBytes + 255) & ~(size_t)255;

    char* ws = (char*)d_ws;
    int*   deg   = (int*)ws;    ws += na * 4;
    int*   start = (int*)ws;    ws += na * 4;
    float* dinv  = (float*)ws;  ws += na * 4;
    int*   bdeg  = (int*)ws;    ws += BMAX * 4;
    int*   bbase = (int*)ws;    ws += BMAX * 4;
    int*   bcur  = (int*)ws;    ws += BMAX * 4;
    int*   csr   = (int*)ws;    ws += (size_t)E * 4;
    __half* xs   = (__half*)ws; ws += (size_t)n * 64 * 2;
    ushort* aggb = (ushort*)ws;
    int*   staging = (int*)aggb;   // aliases aggb: staging dead before gather
    ws += bigBytes;
    ushort* Mb   = (ushort*)ws; ws += 512 * 64 * 2;
    float* cb    = (float*)ws;  ws += 512 * 4;

    hipMemsetAsync(bdeg, 0, BMAX * sizeof(int), stream);

    bucket_hist_kernel<<<1024, 256, 0, stream>>>(dsts, bdeg, E, B);
    bucket_prefix_kernel<<<1, BMAX, 0, stream>>>(bdeg, bbase, bcur, B);
    binning_kernel<<<(E + TILE - 1) / TILE, 512, 0, stream>>>(srcs, dsts, bcur,
                                                              staging, E, B);
    finalize_kernel<<<B, 512, 0, stream>>>(staging, bdeg, bbase, csr, deg, start,
                                           dinv, n);
    build_m_kernel<<<512, 64, 0, stream>>>(Wz, bz, Wh, bh, Lzw, Lzb, Lhw, Lhb,
                                           Mb, cb);
    xs_kernel<<<(n * 16 + 255) / 256, 256, 0, stream>>>(x, dinv, xs, n * 16);
    gather_kernel<<<(n + 3) / 4, 256, 0, stream>>>(csr, start, deg, xs, dinv,
                                                   aggb, n);
    node_mfma_kernel<<<1024, 512, 0, stream>>>(aggb, Mb, cb, Wo, bo, out, n);
}